// Round 3
// baseline (317.541 us; speedup 1.0000x reference)
//
#include <hip/hip_runtime.h>
#include <hip/hip_bf16.h>
#include <math.h>

#define NB 64
#define LD 512
#define LP 1024
#define DD 128
#define KK 64

using half8 = __attribute__((ext_vector_type(8))) _Float16;
using half4 = __attribute__((ext_vector_type(4))) _Float16;
using f32x4 = __attribute__((ext_vector_type(4))) float;

// ---------------- conversion kernels ----------------
__global__ void k_conv(const float* __restrict__ in, _Float16* __restrict__ out, int n) {
    int i = (blockIdx.x * blockDim.x + threadIdx.x) * 4;
    int stride = gridDim.x * blockDim.x * 4;
    for (; i < n; i += stride) {
        float4 v = *reinterpret_cast<const float4*>(in + i);
        half4 h;
        h.x = (_Float16)v.x; h.y = (_Float16)v.y; h.z = (_Float16)v.z; h.w = (_Float16)v.w;
        *reinterpret_cast<half4*>(out + i) = h;
    }
}

__global__ void k_wbt(const float* __restrict__ Wb, _Float16* __restrict__ WbT) {
    int t = blockIdx.x * 256 + threadIdx.x;   // 64 blocks x 256 = 16384
    int d = t >> 7, e = t & 127;
    WbT[t] = (_Float16)Wb[e * 128 + d];
}

__global__ void k_sentinel(float* out) {
    if (threadIdx.x == 0 && blockIdx.x == 0) out[0] = 1000.0f;
}

// ---------------- generic batched NT GEMM, fp16 in, fp16 out ----------------
// Out[b][m,n] = epi( sum_k A[b][m,k] * B[b][n,k] ),  epi = tanh(x + Add[b][m,n])
// A row stride = Kd, B row stride = Kd, Out/Add row stride = N.
// Tiles: BM=64, BN=128, BK=64. 256 threads = 4 waves (2x2), wave tile 32x64.
template<bool TANH, bool ADD>
__global__ __launch_bounds__(256)
void k_gemm(const _Float16* __restrict__ A, long sA,
            const _Float16* __restrict__ Bm, long sB,
            const _Float16* __restrict__ Add, long sAdd,
            _Float16* __restrict__ Out, long sOut,
            int N, int Kd, int tilesM, int tilesN)
{
    __shared__ alignas(16) _Float16 As[64 * 72];
    __shared__ alignas(16) _Float16 Bs[128 * 72];

    int bid = blockIdx.x;
    int tpb = tilesM * tilesN;
    int b = bid / tpb;
    int t = bid % tpb;
    int m0 = (t / tilesN) * 64;
    int n0 = (t % tilesN) * 128;

    const _Float16* Ab = A + (long)b * sA;
    const _Float16* Bb = Bm + (long)b * sB;

    int tid = threadIdx.x;
    int lane = tid & 63;
    int wid = tid >> 6;
    int wm = wid & 1, wn = wid >> 1;

    f32x4 acc[2][4];
#pragma unroll
    for (int i = 0; i < 2; i++)
#pragma unroll
        for (int j = 0; j < 4; j++) acc[i][j] = (f32x4)(0.0f);

    for (int k0 = 0; k0 < Kd; k0 += 64) {
#pragma unroll
        for (int i = 0; i < 2; i++) {           // A tile: 64x64 = 512 16B chunks
            int c = tid + i * 256;
            int row = c >> 3, col = c & 7;
            int4 v = *reinterpret_cast<const int4*>(Ab + (long)(m0 + row) * Kd + k0 + col * 8);
            *reinterpret_cast<int4*>(&As[row * 72 + col * 8]) = v;
        }
#pragma unroll
        for (int i = 0; i < 4; i++) {           // B tile: 128x64 = 1024 16B chunks
            int c = tid + i * 256;
            int row = c >> 3, col = c & 7;
            int4 v = *reinterpret_cast<const int4*>(Bb + (long)(n0 + row) * Kd + k0 + col * 8);
            *reinterpret_cast<int4*>(&Bs[row * 72 + col * 8]) = v;
        }
        __syncthreads();
#pragma unroll
        for (int kk = 0; kk < 64; kk += 32) {
            int klane = kk + 8 * (lane >> 4);
            half8 af[2], bfr[4];
#pragma unroll
            for (int fm = 0; fm < 2; fm++)
                af[fm] = *reinterpret_cast<const half8*>(&As[(wm * 32 + fm * 16 + (lane & 15)) * 72 + klane]);
#pragma unroll
            for (int fn = 0; fn < 4; fn++)
                bfr[fn] = *reinterpret_cast<const half8*>(&Bs[(wn * 64 + fn * 16 + (lane & 15)) * 72 + klane]);
#pragma unroll
            for (int fm = 0; fm < 2; fm++)
#pragma unroll
                for (int fn = 0; fn < 4; fn++)
                    acc[fm][fn] = __builtin_amdgcn_mfma_f32_16x16x32_f16(af[fm], bfr[fn], acc[fm][fn], 0, 0, 0);
        }
        __syncthreads();
    }

    long ob = (long)b * sOut;
    long ab = (long)b * sAdd;
#pragma unroll
    for (int fm = 0; fm < 2; fm++)
#pragma unroll
        for (int fn = 0; fn < 4; fn++)
#pragma unroll
            for (int r = 0; r < 4; r++) {
                int row = m0 + wm * 32 + fm * 16 + (lane >> 4) * 4 + r;
                int col = n0 + wn * 64 + fn * 16 + (lane & 15);
                float v = acc[fm][fn][r];
                if constexpr (ADD) v += (float)Add[ab + (long)row * N + col];
                if constexpr (TANH) v = tanhf(v);
                Out[ob + (long)row * N + col] = (_Float16)v;
            }
}

// ---------------- finalize: scores -> softmax -> weighted sums ----------------
__device__ __forceinline__ float wred_max(float v) {
#pragma unroll
    for (int off = 32; off > 0; off >>= 1) v = fmaxf(v, __shfl_xor(v, off, 64));
    return v;
}
__device__ __forceinline__ float wred_sum(float v) {
#pragma unroll
    for (int off = 32; off > 0; off >>= 1) v += __shfl_xor(v, off, 64);
    return v;
}

__global__ __launch_bounds__(512)
void k_final(const _Float16* __restrict__ Hc, const _Float16* __restrict__ Hp,
             const float* __restrict__ whx, const float* __restrict__ whp,
             const float* __restrict__ drug, const float* __restrict__ target,
             float* __restrict__ outC, float* __restrict__ outP)
{
    __shared__ float a1[LD];
    __shared__ float a2[LP];
    __shared__ float red[512];
    __shared__ float wbuf[64];
    __shared__ float rsc[8];

    int b = blockIdx.x;
    int tid = threadIdx.x;
    int lane = tid & 63, wid = tid >> 6;

    if (tid < 64) wbuf[tid] = whx[tid];
    __syncthreads();

    // ---- drug-side scores: s_c[l] = sum_k whx[k] * Hc[b,k,l], l = tid ----
    float s = 0.f;
    {
        const _Float16* H = Hc + (size_t)b * (KK * LD);
#pragma unroll 4
        for (int k = 0; k < KK; k++) s += wbuf[k] * (float)H[k * LD + tid];
    }
    float m = wred_max(s);
    if (lane == 0) rsc[wid] = m;
    __syncthreads();
    m = rsc[0];
#pragma unroll
    for (int i = 1; i < 8; i++) m = fmaxf(m, rsc[i]);
    float e = __expf(s - m);
    __syncthreads();
    float sm = wred_sum(e);
    if (lane == 0) rsc[wid] = sm;
    __syncthreads();
    sm = 0.f;
#pragma unroll
    for (int i = 0; i < 8; i++) sm += rsc[i];
    a1[tid] = e / sm;
    __syncthreads();

    // ---- c = sum_l a_c[l] * drug[b,l,:] (f32 inputs) ----
    {
        int d = tid & 127, r = tid >> 7;
        float part = 0.f;
        for (int l = r; l < LD; l += 4) part += a1[l] * drug[((size_t)b * LD + l) * DD + d];
        red[tid] = part;
        __syncthreads();
        if (tid < 128) {
            float v = red[tid] + red[tid + 128] + red[tid + 256] + red[tid + 384];
            outC[b * DD + tid] = v;
        }
        __syncthreads();
    }

    // ---- protein-side scores: p = tid and tid+512 ----
    if (tid < 64) wbuf[tid] = whp[tid];
    __syncthreads();
    float s0 = 0.f, s1 = 0.f;
    {
        const _Float16* H = Hp + (size_t)b * (KK * LP);
#pragma unroll 4
        for (int k = 0; k < KK; k++) {
            float wv = wbuf[k];
            s0 += wv * (float)H[k * LP + tid];
            s1 += wv * (float)H[k * LP + tid + 512];
        }
    }
    float m2 = wred_max(fmaxf(s0, s1));
    if (lane == 0) rsc[wid] = m2;
    __syncthreads();
    m2 = rsc[0];
#pragma unroll
    for (int i = 1; i < 8; i++) m2 = fmaxf(m2, rsc[i]);
    float e0 = __expf(s0 - m2), e1 = __expf(s1 - m2);
    __syncthreads();
    float sm2 = wred_sum(e0 + e1);
    if (lane == 0) rsc[wid] = sm2;
    __syncthreads();
    sm2 = 0.f;
#pragma unroll
    for (int i = 0; i < 8; i++) sm2 += rsc[i];
    a2[tid] = e0 / sm2;
    a2[tid + 512] = e1 / sm2;
    __syncthreads();

    // ---- p = sum_pp a_p[pp] * target[b,pp,:] ----
    {
        int d = tid & 127, r = tid >> 7;
        float part = 0.f;
        for (int pp = r; pp < LP; pp += 4) part += a2[pp] * target[((size_t)b * LP + pp) * DD + d];
        red[tid] = part;
        __syncthreads();
        if (tid < 128) {
            float v = red[tid] + red[tid + 128] + red[tid + 256] + red[tid + 384];
            outP[b * DD + tid] = v;
        }
    }
}

// ---------------- launch ----------------
extern "C" void kernel_launch(void* const* d_in, const int* in_sizes, int n_in,
                              void* d_out, int out_size, void* d_ws, size_t ws_size,
                              hipStream_t stream) {
    (void)in_sizes; (void)n_in; (void)out_size;
    const float* drug   = (const float*)d_in[0];
    const float* target = (const float*)d_in[1];
    const float* Wb     = (const float*)d_in[2];
    const float* Wx     = (const float*)d_in[3];
    const float* Wp     = (const float*)d_in[4];
    const float* whx    = (const float*)d_in[5];
    const float* whp    = (const float*)d_in[6];

    char* w = (char*)d_ws;
    size_t off = 0;
    auto take = [&](size_t elems) {
        _Float16* p = (_Float16*)(w + off);
        off += ((elems * 2) + 255) & ~(size_t)255;
        return p;
    };
    _Float16* drug_h = take((size_t)NB * LD * DD);
    _Float16* targ_h = take((size_t)NB * LP * DD);
    _Float16* WbT_h  = take(128 * 128);
    _Float16* Wx_h   = take(64 * 128);
    _Float16* Wp_h   = take(64 * 128);
    _Float16* tb_h   = take((size_t)NB * LP * DD);
    _Float16* Wxd_h  = take((size_t)NB * KK * LD);
    _Float16* Wpt_h  = take((size_t)NB * KK * LP);
    _Float16* C_h    = take((size_t)NB * LP * LD);
    _Float16* CT_h   = take((size_t)NB * LD * LP);
    _Float16* Hc_h   = take((size_t)NB * KK * LD);
    _Float16* Hp_h   = take((size_t)NB * KK * LP);

    if (off > ws_size) {                 // workspace shortfall -> sentinel (absmax ~1000)
        k_sentinel<<<1, 64, 0, stream>>>((float*)d_out);
        return;
    }

    k_conv<<<1024, 256, 0, stream>>>(drug,   drug_h, NB * LD * DD);
    k_conv<<<1024, 256, 0, stream>>>(target, targ_h, NB * LP * DD);
    k_conv<<<16, 256, 0, stream>>>(Wx, Wx_h, 64 * 128);
    k_conv<<<16, 256, 0, stream>>>(Wp, Wp_h, 64 * 128);
    k_wbt<<<64, 256, 0, stream>>>(Wb, WbT_h);

    // tb[p,d] = sum_e target[p,e] * WbT[d,e]            M=LP  N=128 Kd=128
    k_gemm<false, false><<<dim3(NB * (LP / 64) * 1), 256, 0, stream>>>(
        targ_h, (long)LP * DD, WbT_h, 0, nullptr, 0, tb_h, (long)LP * DD, 128, 128, LP / 64, 1);
    // Wxd[k,l] = sum_d Wx[k,d] * drug[l,d]              M=64  N=LD  Kd=128
    k_gemm<false, false><<<dim3(NB * (LD / 128)), 256, 0, stream>>>(
        Wx_h, 0, drug_h, (long)LD * DD, nullptr, 0, Wxd_h, (long)KK * LD, LD, 128, 1, LD / 128);
    // Wpt[k,p] = sum_e Wp[k,e] * target[p,e]            M=64  N=LP  Kd=128
    k_gemm<false, false><<<dim3(NB * (LP / 128)), 256, 0, stream>>>(
        Wp_h, 0, targ_h, (long)LP * DD, nullptr, 0, Wpt_h, (long)KK * LP, LP, 128, 1, LP / 128);
    // C[p,l] = tanh( sum_d tb[p,d] * drug[l,d] )        M=LP  N=LD  Kd=128
    k_gemm<true, false><<<dim3(NB * (LP / 64) * (LD / 128)), 256, 0, stream>>>(
        tb_h, (long)LP * DD, drug_h, (long)LD * DD, nullptr, 0, C_h, (long)LP * LD, LD, 128, LP / 64, LD / 128);
    // CT[l,p] = tanh( sum_d drug[l,d] * tb[p,d] )       M=LD  N=LP  Kd=128
    k_gemm<true, false><<<dim3(NB * (LD / 64) * (LP / 128)), 256, 0, stream>>>(
        drug_h, (long)LD * DD, tb_h, (long)LP * DD, nullptr, 0, CT_h, (long)LD * LP, LP, 128, LD / 64, LP / 128);
    // Hc[k,l] = tanh( Wxd[k,l] + sum_p Wpt[k,p]*CT[l,p] )   M=64 N=LD Kd=LP
    k_gemm<true, true><<<dim3(NB * (LD / 128)), 256, 0, stream>>>(
        Wpt_h, (long)KK * LP, CT_h, (long)LD * LP, Wxd_h, (long)KK * LD, Hc_h, (long)KK * LD, LD, LP, 1, LD / 128);
    // Hp[k,p] = tanh( Wpt[k,p] + sum_l Wxd[k,l]*C[p,l] )    M=64 N=LP Kd=LD
    k_gemm<true, true><<<dim3(NB * (LP / 128)), 256, 0, stream>>>(
        Wxd_h, (long)KK * LD, C_h, (long)LP * LD, Wpt_h, (long)KK * LP, Hp_h, (long)KK * LP, LP, LD, 1, LP / 128);

    k_final<<<NB, 512, 0, stream>>>(Hc_h, Hp_h, whx, whp, drug, target,
                                    (float*)d_out, (float*)d_out + 8192);
}

// Round 5
// 189.870 us; speedup vs baseline: 1.6724x; 1.6724x over previous
//
#include <hip/hip_runtime.h>
#include <hip/hip_bf16.h>
#include <math.h>

#define NB 64
#define LD 512
#define LP 1024
#define DD 128
#define KK 64

using half8 = __attribute__((ext_vector_type(8))) _Float16;
using half4 = __attribute__((ext_vector_type(4))) _Float16;
using f32x4 = __attribute__((ext_vector_type(4))) float;

// ---------------- conversion kernels ----------------
__global__ void k_conv(const float* __restrict__ in, _Float16* __restrict__ out, int n) {
    int i = (blockIdx.x * blockDim.x + threadIdx.x) * 4;
    int stride = gridDim.x * blockDim.x * 4;
    for (; i < n; i += stride) {
        float4 v = *reinterpret_cast<const float4*>(in + i);
        half4 h;
        h.x = (_Float16)v.x; h.y = (_Float16)v.y; h.z = (_Float16)v.z; h.w = (_Float16)v.w;
        *reinterpret_cast<half4*>(out + i) = h;
    }
}

__global__ void k_wbt(const float* __restrict__ Wb, _Float16* __restrict__ WbT) {
    int t = blockIdx.x * 256 + threadIdx.x;   // 64 blocks x 256 = 16384
    int d = t >> 7, e = t & 127;
    WbT[t] = (_Float16)Wb[e * 128 + d];
}

__global__ void k_sentinel(float* out) {
    if (threadIdx.x == 0 && blockIdx.x == 0) out[0] = 1000.0f;
}

// ---------------- plain batched NT GEMM, fp16 in/out (tb, Wxd, Wpt) ----------------
// Out[b][m,n] = sum_k A[b][m,k] * B[b][n,k].  BM=64, BN=128, BK=64, 4 waves 2x2.
__global__ __launch_bounds__(256)
void k_gemm(const _Float16* __restrict__ A, long sA,
            const _Float16* __restrict__ Bm, long sB,
            _Float16* __restrict__ Out, long sOut,
            int N, int Kd, int tilesM, int tilesN)
{
    __shared__ alignas(16) _Float16 smem[64 * 72 + 128 * 72];
    _Float16* As = smem;
    _Float16* Bs = smem + 64 * 72;

    int bid = blockIdx.x;
    int tpb = tilesM * tilesN;
    int b = bid / tpb;
    int t = bid % tpb;
    int m0 = (t / tilesN) * 64;
    int n0 = (t % tilesN) * 128;

    const _Float16* Ab = A + (long)b * sA;
    const _Float16* Bb = Bm + (long)b * sB;

    int tid = threadIdx.x;
    int lane = tid & 63;
    int wid = tid >> 6;
    int wm = wid & 1, wn = wid >> 1;

    f32x4 acc[2][4];
#pragma unroll
    for (int i = 0; i < 2; i++)
#pragma unroll
        for (int j = 0; j < 4; j++) acc[i][j] = (f32x4)(0.0f);

    for (int k0 = 0; k0 < Kd; k0 += 64) {
#pragma unroll
        for (int i = 0; i < 2; i++) {
            int c = tid + i * 256;
            int row = c >> 3, col = c & 7;
            int4 v = *reinterpret_cast<const int4*>(Ab + (long)(m0 + row) * Kd + k0 + col * 8);
            *reinterpret_cast<int4*>(&As[row * 72 + col * 8]) = v;
        }
#pragma unroll
        for (int i = 0; i < 4; i++) {
            int c = tid + i * 256;
            int row = c >> 3, col = c & 7;
            int4 v = *reinterpret_cast<const int4*>(Bb + (long)(n0 + row) * Kd + k0 + col * 8);
            *reinterpret_cast<int4*>(&Bs[row * 72 + col * 8]) = v;
        }
        __syncthreads();
#pragma unroll
        for (int kk = 0; kk < 64; kk += 32) {
            int klane = kk + 8 * (lane >> 4);
            half8 af[2], bfr[4];
#pragma unroll
            for (int fm = 0; fm < 2; fm++)
                af[fm] = *reinterpret_cast<const half8*>(&As[(wm * 32 + fm * 16 + (lane & 15)) * 72 + klane]);
#pragma unroll
            for (int fn = 0; fn < 4; fn++)
                bfr[fn] = *reinterpret_cast<const half8*>(&Bs[(wn * 64 + fn * 16 + (lane & 15)) * 72 + klane]);
#pragma unroll
            for (int fm = 0; fm < 2; fm++)
#pragma unroll
                for (int fn = 0; fn < 4; fn++)
                    acc[fm][fn] = __builtin_amdgcn_mfma_f32_16x16x32_f16(af[fm], bfr[fn], acc[fm][fn], 0, 0, 0);
        }
        __syncthreads();
    }

    long ob = (long)b * sOut;
#pragma unroll
    for (int fm = 0; fm < 2; fm++)
#pragma unroll
        for (int fn = 0; fn < 4; fn++)
#pragma unroll
            for (int r = 0; r < 4; r++) {
                int row = m0 + wm * 32 + fm * 16 + (lane >> 4) * 4 + r;
                int col = n0 + wn * 64 + fn * 16 + (lane & 15);
                Out[ob + (long)row * N + col] = (_Float16)acc[fm][fn][r];
            }
}

// ---------------- C GEMM: writes tanh(C) AND tanh(C)^T (LDS transpose) ----------------
// C[b][p,l] = tanh( sum_d tb[p,d] * drug[l,d] ),  CT[b][l,p] = C[b][p,l]
__global__ __launch_bounds__(256)
void k_gemm_ct(const _Float16* __restrict__ A, long sA,      // tb [LP,DD]
               const _Float16* __restrict__ Bm, long sB,     // drug [LD,DD]
               _Float16* __restrict__ OutC, long sOutC,      // [LP,LD]
               _Float16* __restrict__ OutT, long sOutT,      // [LD,LP]
               int N, int NT, int Kd, int tilesM, int tilesN)
{
    __shared__ alignas(16) _Float16 smem[64 * 72 + 128 * 72];
    _Float16* As = smem;
    _Float16* Bs = smem + 64 * 72;
    _Float16* T  = smem;                      // overlay: 128 rows x 72 pitch (p cols)

    int bid = blockIdx.x;
    int tpb = tilesM * tilesN;
    int b = bid / tpb;
    int t = bid % tpb;
    int m0 = (t / tilesN) * 64;               // p offset
    int n0 = (t % tilesN) * 128;              // l offset

    const _Float16* Ab = A + (long)b * sA;
    const _Float16* Bb = Bm + (long)b * sB;

    int tid = threadIdx.x;
    int lane = tid & 63;
    int wid = tid >> 6;
    int wm = wid & 1, wn = wid >> 1;

    f32x4 acc[2][4];
#pragma unroll
    for (int i = 0; i < 2; i++)
#pragma unroll
        for (int j = 0; j < 4; j++) acc[i][j] = (f32x4)(0.0f);

    for (int k0 = 0; k0 < Kd; k0 += 64) {
#pragma unroll
        for (int i = 0; i < 2; i++) {
            int c = tid + i * 256;
            int row = c >> 3, col = c & 7;
            int4 v = *reinterpret_cast<const int4*>(Ab + (long)(m0 + row) * Kd + k0 + col * 8);
            *reinterpret_cast<int4*>(&As[row * 72 + col * 8]) = v;
        }
#pragma unroll
        for (int i = 0; i < 4; i++) {
            int c = tid + i * 256;
            int row = c >> 3, col = c & 7;
            int4 v = *reinterpret_cast<const int4*>(Bb + (long)(n0 + row) * Kd + k0 + col * 8);
            *reinterpret_cast<int4*>(&Bs[row * 72 + col * 8]) = v;
        }
        __syncthreads();
#pragma unroll
        for (int kk = 0; kk < 64; kk += 32) {
            int klane = kk + 8 * (lane >> 4);
            half8 af[2], bfr[4];
#pragma unroll
            for (int fm = 0; fm < 2; fm++)
                af[fm] = *reinterpret_cast<const half8*>(&As[(wm * 32 + fm * 16 + (lane & 15)) * 72 + klane]);
#pragma unroll
            for (int fn = 0; fn < 4; fn++)
                bfr[fn] = *reinterpret_cast<const half8*>(&Bs[(wn * 64 + fn * 16 + (lane & 15)) * 72 + klane]);
#pragma unroll
            for (int fm = 0; fm < 2; fm++)
#pragma unroll
                for (int fn = 0; fn < 4; fn++)
                    acc[fm][fn] = __builtin_amdgcn_mfma_f32_16x16x32_f16(af[fm], bfr[fn], acc[fm][fn], 0, 0, 0);
        }
        __syncthreads();
    }

    long ob = (long)b * sOutC;
#pragma unroll
    for (int fm = 0; fm < 2; fm++)
#pragma unroll
        for (int fn = 0; fn < 4; fn++)
#pragma unroll
            for (int r = 0; r < 4; r++) {
                int lp = wm * 32 + fm * 16 + (lane >> 4) * 4 + r;   // local p
                int ll = wn * 64 + fn * 16 + (lane & 15);           // local l
                _Float16 hv = (_Float16)tanhf(acc[fm][fn][r]);
                OutC[ob + (long)(m0 + lp) * N + n0 + ll] = hv;
                T[ll * 72 + lp] = hv;
            }
    __syncthreads();
    long obT = (long)b * sOutT;
#pragma unroll
    for (int i = 0; i < 4; i++) {
        int chunk = tid + i * 256;          // 1024 chunks of 16B
        int rowT = chunk >> 3;              // local l 0..127
        int cp = (chunk & 7) * 8;           // local p 0..56
        int4 v = *reinterpret_cast<const int4*>(&T[rowT * 72 + cp]);
        *reinterpret_cast<int4*>(&OutT[obT + (long)(n0 + rowT) * NT + m0 + cp]) = v;
    }
}

// ---------------- H GEMM + fused score: sc[b,n] = sum_k w[k]*tanh(acc+Add) ----------------
// BM=64 (= all K rows), BN=128. No H output.
__global__ __launch_bounds__(256)
void k_gemm_score(const _Float16* __restrict__ A, long sA,
                  const _Float16* __restrict__ Bm, long sB,
                  const _Float16* __restrict__ Add, long sAdd,
                  const float* __restrict__ wv,
                  float* __restrict__ sc,
                  int N, int Kd, int tilesN)
{
    __shared__ alignas(16) _Float16 smem[64 * 72 + 128 * 72];
    __shared__ float sred[8 * 128];
    __shared__ float wsh[64];
    _Float16* As = smem;
    _Float16* Bs = smem + 64 * 72;

    int bid = blockIdx.x;
    int b = bid / tilesN;
    int n0 = (bid % tilesN) * 128;

    const _Float16* Ab = A + (long)b * sA;
    const _Float16* Bb = Bm + (long)b * sB;

    int tid = threadIdx.x;
    int lane = tid & 63;
    int wid = tid >> 6;
    int wm = wid & 1, wn = wid >> 1;

    if (tid < 64) wsh[tid] = wv[tid];       // synced by first loop barrier

    f32x4 acc[2][4];
#pragma unroll
    for (int i = 0; i < 2; i++)
#pragma unroll
        for (int j = 0; j < 4; j++) acc[i][j] = (f32x4)(0.0f);

    for (int k0 = 0; k0 < Kd; k0 += 64) {
#pragma unroll
        for (int i = 0; i < 2; i++) {
            int c = tid + i * 256;
            int row = c >> 3, col = c & 7;
            int4 v = *reinterpret_cast<const int4*>(Ab + (long)row * Kd + k0 + col * 8);
            *reinterpret_cast<int4*>(&As[row * 72 + col * 8]) = v;
        }
#pragma unroll
        for (int i = 0; i < 4; i++) {
            int c = tid + i * 256;
            int row = c >> 3, col = c & 7;
            int4 v = *reinterpret_cast<const int4*>(Bb + (long)(n0 + row) * Kd + k0 + col * 8);
            *reinterpret_cast<int4*>(&Bs[row * 72 + col * 8]) = v;
        }
        __syncthreads();
#pragma unroll
        for (int kk = 0; kk < 64; kk += 32) {
            int klane = kk + 8 * (lane >> 4);
            half8 af[2], bfr[4];
#pragma unroll
            for (int fm = 0; fm < 2; fm++)
                af[fm] = *reinterpret_cast<const half8*>(&As[(wm * 32 + fm * 16 + (lane & 15)) * 72 + klane]);
#pragma unroll
            for (int fn = 0; fn < 4; fn++)
                bfr[fn] = *reinterpret_cast<const half8*>(&Bs[(wn * 64 + fn * 16 + (lane & 15)) * 72 + klane]);
#pragma unroll
            for (int fm = 0; fm < 2; fm++)
#pragma unroll
                for (int fn = 0; fn < 4; fn++)
                    acc[fm][fn] = __builtin_amdgcn_mfma_f32_16x16x32_f16(af[fm], bfr[fn], acc[fm][fn], 0, 0, 0);
        }
        __syncthreads();
    }

    long ab = (long)b * sAdd;
    float ps[4] = {0.f, 0.f, 0.f, 0.f};
#pragma unroll
    for (int fm = 0; fm < 2; fm++)
#pragma unroll
        for (int fn = 0; fn < 4; fn++)
#pragma unroll
            for (int r = 0; r < 4; r++) {
                int krow = wm * 32 + fm * 16 + (lane >> 4) * 4 + r;
                int col = n0 + wn * 64 + fn * 16 + (lane & 15);
                float v = tanhf(acc[fm][fn][r] + (float)Add[ab + (long)krow * N + col]);
                ps[fn] += wsh[krow] * v;
            }
#pragma unroll
    for (int fn = 0; fn < 4; fn++)
        sred[(wm * 4 + (lane >> 4)) * 128 + wn * 64 + fn * 16 + (lane & 15)] = ps[fn];
    __syncthreads();
    if (tid < 128) {
        float s = 0.f;
#pragma unroll
        for (int j = 0; j < 8; j++) s += sred[j * 128 + tid];
        sc[(long)b * N + n0 + tid] = s;
    }
}

// ---------------- softmax over scores ----------------
__device__ __forceinline__ float wred_max(float v) {
#pragma unroll
    for (int off = 32; off > 0; off >>= 1) v = fmaxf(v, __shfl_xor(v, off, 64));
    return v;
}
__device__ __forceinline__ float wred_sum(float v) {
#pragma unroll
    for (int off = 32; off > 0; off >>= 1) v += __shfl_xor(v, off, 64);
    return v;
}

__global__ __launch_bounds__(1024)
void k_soft(const float* __restrict__ scc, const float* __restrict__ scp,
            float* __restrict__ ac, float* __restrict__ ap)
{
    __shared__ float r16[16];
    int b = blockIdx.x, tid = threadIdx.x;
    int lane = tid & 63, wid = tid >> 6;

    // drug side (512)
    float s = (tid < 512) ? scc[b * 512 + tid] : -3.4e38f;
    float m = wred_max(s);
    if (lane == 0) r16[wid] = m;
    __syncthreads();
    m = r16[0];
#pragma unroll
    for (int i = 1; i < 16; i++) m = fmaxf(m, r16[i]);
    float e = (tid < 512) ? __expf(s - m) : 0.f;
    __syncthreads();
    float t = wred_sum(e);
    if (lane == 0) r16[wid] = t;
    __syncthreads();
    float sum = 0.f;
#pragma unroll
    for (int i = 0; i < 16; i++) sum += r16[i];
    if (tid < 512) ac[b * 512 + tid] = e / sum;
    __syncthreads();

    // protein side (1024)
    float s2 = scp[b * 1024 + tid];
    float m2 = wred_max(s2);
    if (lane == 0) r16[wid] = m2;
    __syncthreads();
    m2 = r16[0];
#pragma unroll
    for (int i = 1; i < 16; i++) m2 = fmaxf(m2, r16[i]);
    float e2 = __expf(s2 - m2);
    __syncthreads();
    float t2 = wred_sum(e2);
    if (lane == 0) r16[wid] = t2;
    __syncthreads();
    float sum2 = 0.f;
#pragma unroll
    for (int i = 0; i < 16; i++) sum2 += r16[i];
    ap[b * 1024 + tid] = e2 / sum2;
}

// ---------------- weighted sums: out[b,d] = sum_l a[l] * X[b,l,d] ----------------
__global__ __launch_bounds__(512)
void k_wsum(const _Float16* __restrict__ drug_h, const _Float16* __restrict__ targ_h,
            const float* __restrict__ ac, const float* __restrict__ ap,
            float* __restrict__ out)
{
    __shared__ float ash[1024];
    __shared__ float red[32 * 128];
    int b = blockIdx.x, side = blockIdx.y;
    int L = side ? LP : LD;
    const _Float16* X = side ? targ_h : drug_h;
    const float* a = side ? ap : ac;
    float* ob = out + side * 8192 + b * 128;
    int tid = threadIdx.x;

    for (int i = tid; i < L; i += 512) ash[i] = a[(long)b * L + i];
    __syncthreads();

    int col8 = tid & 15, rg = tid >> 4;
    float accv[8];
#pragma unroll
    for (int j = 0; j < 8; j++) accv[j] = 0.f;
    const _Float16* Xb = X + (long)b * L * 128;
    for (int l = rg; l < L; l += 32) {
        half8 v = *reinterpret_cast<const half8*>(&Xb[l * 128 + col8 * 8]);
        float av = ash[l];
#pragma unroll
        for (int j = 0; j < 8; j++) accv[j] += av * (float)v[j];
    }
#pragma unroll
    for (int j = 0; j < 8; j++) red[rg * 128 + col8 * 8 + j] = accv[j];
    __syncthreads();
    if (tid < 128) {
        float s = 0.f;
#pragma unroll
        for (int g = 0; g < 32; g++) s += red[g * 128 + tid];
        ob[tid] = s;
    }
}

// ---------------- launch ----------------
extern "C" void kernel_launch(void* const* d_in, const int* in_sizes, int n_in,
                              void* d_out, int out_size, void* d_ws, size_t ws_size,
                              hipStream_t stream) {
    (void)in_sizes; (void)n_in; (void)out_size;
    const float* drug   = (const float*)d_in[0];
    const float* target = (const float*)d_in[1];
    const float* Wb     = (const float*)d_in[2];
    const float* Wx     = (const float*)d_in[3];
    const float* Wp     = (const float*)d_in[4];
    const float* whx    = (const float*)d_in[5];
    const float* whp    = (const float*)d_in[6];

    char* w = (char*)d_ws;
    size_t off = 0;
    auto takeb = [&](size_t bytes) {
        void* p = (void*)(w + off);
        off += (bytes + 255) & ~(size_t)255;
        return p;
    };
    _Float16* drug_h = (_Float16*)takeb((size_t)NB * LD * DD * 2);
    _Float16* targ_h = (_Float16*)takeb((size_t)NB * LP * DD * 2);
    _Float16* WbT_h  = (_Float16*)takeb(128 * 128 * 2);
    _Float16* Wx_h   = (_Float16*)takeb(64 * 128 * 2);
    _Float16* Wp_h   = (_Float16*)takeb(64 * 128 * 2);
    _Float16* tb_h   = (_Float16*)takeb((size_t)NB * LP * DD * 2);
    _Float16* Wxd_h  = (_Float16*)takeb((size_t)NB * KK * LD * 2);
    _Float16* Wpt_h  = (_Float16*)takeb((size_t)NB * KK * LP * 2);
    _Float16* C_h    = (_Float16*)takeb((size_t)NB * LP * LD * 2);
    _Float16* CT_h   = (_Float16*)takeb((size_t)NB * LD * LP * 2);
    float*    sc_c   = (float*)takeb((size_t)NB * LD * 4);
    float*    sc_p   = (float*)takeb((size_t)NB * LP * 4);
    float*    a_c    = (float*)takeb((size_t)NB * LD * 4);
    float*    a_p    = (float*)takeb((size_t)NB * LP * 4);

    if (off > ws_size) {                 // workspace shortfall -> sentinel (absmax ~1000)
        k_sentinel<<<1, 64, 0, stream>>>((float*)d_out);
        return;
    }

    k_conv<<<1024, 256, 0, stream>>>(drug,   drug_h, NB * LD * DD);
    k_conv<<<1024, 256, 0, stream>>>(target, targ_h, NB * LP * DD);
    k_conv<<<16, 256, 0, stream>>>(Wx, Wx_h, 64 * 128);
    k_conv<<<16, 256, 0, stream>>>(Wp, Wp_h, 64 * 128);
    k_wbt<<<64, 256, 0, stream>>>(Wb, WbT_h);

    // tb[p,d] = sum_e target[p,e] * WbT[d,e]            M=LP  N=128 Kd=128
    k_gemm<<<dim3(NB * (LP / 64)), 256, 0, stream>>>(
        targ_h, (long)LP * DD, WbT_h, 0, tb_h, (long)LP * DD, 128, 128, LP / 64, 1);
    // Wxd[k,l] = sum_d Wx[k,d] * drug[l,d]              M=64  N=LD  Kd=128
    k_gemm<<<dim3(NB * (LD / 128)), 256, 0, stream>>>(
        Wx_h, 0, drug_h, (long)LD * DD, Wxd_h, (long)KK * LD, LD, 128, 1, LD / 128);
    // Wpt[k,p] = sum_e Wp[k,e] * target[p,e]            M=64  N=LP  Kd=128
    k_gemm<<<dim3(NB * (LP / 128)), 256, 0, stream>>>(
        Wp_h, 0, targ_h, (long)LP * DD, Wpt_h, (long)KK * LP, LP, 128, 1, LP / 128);
    // C[p,l] = tanh(tb . drug^T), CT = C^T              M=LP  N=LD  Kd=128
    k_gemm_ct<<<dim3(NB * (LP / 64) * (LD / 128)), 256, 0, stream>>>(
        tb_h, (long)LP * DD, drug_h, (long)LD * DD,
        C_h, (long)LP * LD, CT_h, (long)LD * LP, LD, LP, 128, LP / 64, LD / 128);
    // sc_c[l] = sum_k whx[k]*tanh(Wxd[k,l] + sum_p Wpt[k,p]*CT[l,p])   Kd=LP
    k_gemm_score<<<dim3(NB * (LD / 128)), 256, 0, stream>>>(
        Wpt_h, (long)KK * LP, CT_h, (long)LD * LP, Wxd_h, (long)KK * LD,
        whx, sc_c, LD, LP, LD / 128);
    // sc_p[p] = sum_k whp[k]*tanh(Wpt[k,p] + sum_l Wxd[k,l]*C[p,l])    Kd=LD
    k_gemm_score<<<dim3(NB * (LP / 128)), 256, 0, stream>>>(
        Wxd_h, (long)KK * LD, C_h, (long)LP * LD, Wpt_h, (long)KK * LP,
        whp, sc_p, LP, LD, LP / 128);

    k_soft<<<NB, 1024, 0, stream>>>(sc_c, sc_p, a_c, a_p);
    k_wsum<<<dim3(NB, 2), 512, 0, stream>>>(drug_h, targ_h, a_c, a_p, (float*)d_out);
}

// Round 7
// 172.118 us; speedup vs baseline: 1.8449x; 1.1031x over previous
//
#include <hip/hip_runtime.h>
#include <hip/hip_bf16.h>
#include <math.h>

#define NB 64
#define LD 512
#define LP 1024
#define DD 128
#define KK 64

using half8 = __attribute__((ext_vector_type(8))) _Float16;
using half4 = __attribute__((ext_vector_type(4))) _Float16;
using f32x4 = __attribute__((ext_vector_type(4))) float;

// fast tanh: 1 - 2/(e^{2x}+1); inf-safe both tails (x>>0: e=inf -> 1; x<<0: e=0 -> -1)
__device__ __forceinline__ float ftanh(float x) {
    float e = __expf(2.0f * x);
    return 1.0f - 2.0f / (e + 1.0f);
}

// ---------------- conversion kernels ----------------
__global__ void k_conv(const float* __restrict__ in, _Float16* __restrict__ out, int n) {
    int i = (blockIdx.x * blockDim.x + threadIdx.x) * 4;
    int stride = gridDim.x * blockDim.x * 4;
    for (; i < n; i += stride) {
        float4 v = *reinterpret_cast<const float4*>(in + i);
        half4 h;
        h.x = (_Float16)v.x; h.y = (_Float16)v.y; h.z = (_Float16)v.z; h.w = (_Float16)v.w;
        *reinterpret_cast<half4*>(out + i) = h;
    }
}

__global__ void k_wbt(const float* __restrict__ Wb, _Float16* __restrict__ WbT) {
    int t = blockIdx.x * 256 + threadIdx.x;   // 64 blocks x 256 = 16384
    int d = t >> 7, e = t & 127;
    WbT[t] = (_Float16)Wb[e * 128 + d];
}

__global__ void k_sentinel(float* out) {
    if (threadIdx.x == 0 && blockIdx.x == 0) out[0] = 1000.0f;
}

// ---------------- plain batched NT GEMM, fp16 in/out (tb, Wxd, Wpt) ----------------
// Out[b][m,n] = sum_k A[b][m,k] * B[b][n,k].  BM=64, BN=128, BK=64, 4 waves 2x2.
__global__ __launch_bounds__(256)
void k_gemm(const _Float16* __restrict__ A, long sA,
            const _Float16* __restrict__ Bm, long sB,
            _Float16* __restrict__ Out, long sOut,
            int N, int Kd, int tilesM, int tilesN)
{
    __shared__ alignas(16) _Float16 smem[64 * 72 + 128 * 72];
    _Float16* As = smem;
    _Float16* Bs = smem + 64 * 72;

    int bid = blockIdx.x;
    int tpb = tilesM * tilesN;
    int b = bid / tpb;
    int t = bid % tpb;
    int m0 = (t / tilesN) * 64;
    int n0 = (t % tilesN) * 128;

    const _Float16* Ab = A + (long)b * sA;
    const _Float16* Bb = Bm + (long)b * sB;

    int tid = threadIdx.x;
    int lane = tid & 63;
    int wid = tid >> 6;
    int wm = wid & 1, wn = wid >> 1;

    f32x4 acc[2][4];
#pragma unroll
    for (int i = 0; i < 2; i++)
#pragma unroll
        for (int j = 0; j < 4; j++) acc[i][j] = (f32x4)(0.0f);

    for (int k0 = 0; k0 < Kd; k0 += 64) {
#pragma unroll
        for (int i = 0; i < 2; i++) {
            int c = tid + i * 256;
            int row = c >> 3, col = c & 7;
            int4 v = *reinterpret_cast<const int4*>(Ab + (long)(m0 + row) * Kd + k0 + col * 8);
            *reinterpret_cast<int4*>(&As[row * 72 + col * 8]) = v;
        }
#pragma unroll
        for (int i = 0; i < 4; i++) {
            int c = tid + i * 256;
            int row = c >> 3, col = c & 7;
            int4 v = *reinterpret_cast<const int4*>(Bb + (long)(n0 + row) * Kd + k0 + col * 8);
            *reinterpret_cast<int4*>(&Bs[row * 72 + col * 8]) = v;
        }
        __syncthreads();
#pragma unroll
        for (int kk = 0; kk < 64; kk += 32) {
            int klane = kk + 8 * (lane >> 4);
            half8 af[2], bfr[4];
#pragma unroll
            for (int fm = 0; fm < 2; fm++)
                af[fm] = *reinterpret_cast<const half8*>(&As[(wm * 32 + fm * 16 + (lane & 15)) * 72 + klane]);
#pragma unroll
            for (int fn = 0; fn < 4; fn++)
                bfr[fn] = *reinterpret_cast<const half8*>(&Bs[(wn * 64 + fn * 16 + (lane & 15)) * 72 + klane]);
#pragma unroll
            for (int fm = 0; fm < 2; fm++)
#pragma unroll
                for (int fn = 0; fn < 4; fn++)
                    acc[fm][fn] = __builtin_amdgcn_mfma_f32_16x16x32_f16(af[fm], bfr[fn], acc[fm][fn], 0, 0, 0);
        }
        __syncthreads();
    }

    long ob = (long)b * sOut;
#pragma unroll
    for (int fm = 0; fm < 2; fm++)
#pragma unroll
        for (int fn = 0; fn < 4; fn++)
#pragma unroll
            for (int r = 0; r < 4; r++) {
                int row = m0 + wm * 32 + fm * 16 + (lane >> 4) * 4 + r;
                int col = n0 + wn * 64 + fn * 16 + (lane & 15);
                Out[ob + (long)row * N + col] = (_Float16)acc[fm][fn][r];
            }
}

// ---------------- C GEMM: writes tanh(C) AND tanh(C)^T, both via LDS repack ----------------
// C[b][p,l] = tanh( sum_d tb[p,d] * drug[l,d] ),  CT[b][l,p] = C[b][p,l]
// Epilogue: scatter acc (b16, <=4-way conflicts) into two LDS overlays, then
// fully-coalesced int4 global stores for BOTH orientations.
__global__ __launch_bounds__(256)
void k_gemm_ct(const _Float16* __restrict__ A, long sA,      // tb [LP,DD]
               const _Float16* __restrict__ Bm, long sB,     // drug [LD,DD]
               _Float16* __restrict__ OutC, long sOutC,      // [LP,LD]
               _Float16* __restrict__ OutT, long sOutT,      // [LD,LP]
               int N, int NT, int Kd, int tilesM, int tilesN)
{
    __shared__ alignas(16) _Float16 smem[17920];   // 35840 B
    _Float16* As = smem;                            // [64][72]
    _Float16* Bs = smem + 64 * 72;                  // [128][72]
    _Float16* T  = smem;                            // overlay: [128 l][72]  (9216)
    _Float16* C2 = smem + 9216;                     // overlay: [64 p][136]  (8704)

    int bid = blockIdx.x;
    int tpb = tilesM * tilesN;
    int b = bid / tpb;
    int t = bid % tpb;
    int m0 = (t / tilesN) * 64;               // p offset
    int n0 = (t % tilesN) * 128;              // l offset

    const _Float16* Ab = A + (long)b * sA;
    const _Float16* Bb = Bm + (long)b * sB;

    int tid = threadIdx.x;
    int lane = tid & 63;
    int wid = tid >> 6;
    int wm = wid & 1, wn = wid >> 1;

    f32x4 acc[2][4];
#pragma unroll
    for (int i = 0; i < 2; i++)
#pragma unroll
        for (int j = 0; j < 4; j++) acc[i][j] = (f32x4)(0.0f);

    for (int k0 = 0; k0 < Kd; k0 += 64) {
#pragma unroll
        for (int i = 0; i < 2; i++) {
            int c = tid + i * 256;
            int row = c >> 3, col = c & 7;
            int4 v = *reinterpret_cast<const int4*>(Ab + (long)(m0 + row) * Kd + k0 + col * 8);
            *reinterpret_cast<int4*>(&As[row * 72 + col * 8]) = v;
        }
#pragma unroll
        for (int i = 0; i < 4; i++) {
            int c = tid + i * 256;
            int row = c >> 3, col = c & 7;
            int4 v = *reinterpret_cast<const int4*>(Bb + (long)(n0 + row) * Kd + k0 + col * 8);
            *reinterpret_cast<int4*>(&Bs[row * 72 + col * 8]) = v;
        }
        __syncthreads();
#pragma unroll
        for (int kk = 0; kk < 64; kk += 32) {
            int klane = kk + 8 * (lane >> 4);
            half8 af[2], bfr[4];
#pragma unroll
            for (int fm = 0; fm < 2; fm++)
                af[fm] = *reinterpret_cast<const half8*>(&As[(wm * 32 + fm * 16 + (lane & 15)) * 72 + klane]);
#pragma unroll
            for (int fn = 0; fn < 4; fn++)
                bfr[fn] = *reinterpret_cast<const half8*>(&Bs[(wn * 64 + fn * 16 + (lane & 15)) * 72 + klane]);
#pragma unroll
            for (int fm = 0; fm < 2; fm++)
#pragma unroll
                for (int fn = 0; fn < 4; fn++)
                    acc[fm][fn] = __builtin_amdgcn_mfma_f32_16x16x32_f16(af[fm], bfr[fn], acc[fm][fn], 0, 0, 0);
        }
        __syncthreads();
    }

    // scatter tanh'd acc into both LDS orientations
#pragma unroll
    for (int fm = 0; fm < 2; fm++)
#pragma unroll
        for (int fn = 0; fn < 4; fn++)
#pragma unroll
            for (int r = 0; r < 4; r++) {
                int lp = wm * 32 + fm * 16 + (lane >> 4) * 4 + r;   // local p
                int ll = wn * 64 + fn * 16 + (lane & 15);           // local l
                _Float16 hv = (_Float16)ftanh(acc[fm][fn][r]);
                T[ll * 72 + lp] = hv;
                C2[lp * 136 + ll] = hv;
            }
    __syncthreads();

    long ob  = (long)b * sOutC;
    long obT = (long)b * sOutT;
#pragma unroll
    for (int i = 0; i < 4; i++) {
        int c = tid + i * 256;
        {   // C store: 16 int4 per p-row (256 B runs)
            int p = c >> 4, l8 = (c & 15) * 8;
            int4 v = *reinterpret_cast<const int4*>(&C2[p * 136 + l8]);
            *reinterpret_cast<int4*>(&OutC[ob + (long)(m0 + p) * N + n0 + l8]) = v;
        }
        {   // CT store: 8 int4 per l-row (128 B runs)
            int rowT = c >> 3, cp = (c & 7) * 8;
            int4 v = *reinterpret_cast<const int4*>(&T[rowT * 72 + cp]);
            *reinterpret_cast<int4*>(&OutT[obT + (long)(n0 + rowT) * NT + m0 + cp]) = v;
        }
    }
}

// ---------------- H GEMM + fused score: sc[b,n] = sum_k w[k]*tanh(acc+Add) ----------------
// BM=64 (= all K rows), BN=128. No H output.
__global__ __launch_bounds__(256)
void k_gemm_score(const _Float16* __restrict__ A, long sA,
                  const _Float16* __restrict__ Bm, long sB,
                  const _Float16* __restrict__ Add, long sAdd,
                  const float* __restrict__ wv,
                  float* __restrict__ sc,
                  int N, int Kd, int tilesN)
{
    __shared__ alignas(16) _Float16 smem[64 * 72 + 128 * 72];
    __shared__ float sred[8 * 128];
    __shared__ float wsh[64];
    _Float16* As = smem;
    _Float16* Bs = smem + 64 * 72;

    int bid = blockIdx.x;
    int b = bid / tilesN;
    int n0 = (bid % tilesN) * 128;

    const _Float16* Ab = A + (long)b * sA;
    const _Float16* Bb = Bm + (long)b * sB;

    int tid = threadIdx.x;
    int lane = tid & 63;
    int wid = tid >> 6;
    int wm = wid & 1, wn = wid >> 1;

    if (tid < 64) wsh[tid] = wv[tid];       // synced by first loop barrier

    f32x4 acc[2][4];
#pragma unroll
    for (int i = 0; i < 2; i++)
#pragma unroll
        for (int j = 0; j < 4; j++) acc[i][j] = (f32x4)(0.0f);

    for (int k0 = 0; k0 < Kd; k0 += 64) {
#pragma unroll
        for (int i = 0; i < 2; i++) {
            int c = tid + i * 256;
            int row = c >> 3, col = c & 7;
            int4 v = *reinterpret_cast<const int4*>(Ab + (long)row * Kd + k0 + col * 8);
            *reinterpret_cast<int4*>(&As[row * 72 + col * 8]) = v;
        }
#pragma unroll
        for (int i = 0; i < 4; i++) {
            int c = tid + i * 256;
            int row = c >> 3, col = c & 7;
            int4 v = *reinterpret_cast<const int4*>(Bb + (long)(n0 + row) * Kd + k0 + col * 8);
            *reinterpret_cast<int4*>(&Bs[row * 72 + col * 8]) = v;
        }
        __syncthreads();
#pragma unroll
        for (int kk = 0; kk < 64; kk += 32) {
            int klane = kk + 8 * (lane >> 4);
            half8 af[2], bfr[4];
#pragma unroll
            for (int fm = 0; fm < 2; fm++)
                af[fm] = *reinterpret_cast<const half8*>(&As[(wm * 32 + fm * 16 + (lane & 15)) * 72 + klane]);
#pragma unroll
            for (int fn = 0; fn < 4; fn++)
                bfr[fn] = *reinterpret_cast<const half8*>(&Bs[(wn * 64 + fn * 16 + (lane & 15)) * 72 + klane]);
#pragma unroll
            for (int fm = 0; fm < 2; fm++)
#pragma unroll
                for (int fn = 0; fn < 4; fn++)
                    acc[fm][fn] = __builtin_amdgcn_mfma_f32_16x16x32_f16(af[fm], bfr[fn], acc[fm][fn], 0, 0, 0);
        }
        __syncthreads();
    }

    long ab = (long)b * sAdd;
    float ps[4] = {0.f, 0.f, 0.f, 0.f};
#pragma unroll
    for (int fm = 0; fm < 2; fm++)
#pragma unroll
        for (int fn = 0; fn < 4; fn++)
#pragma unroll
            for (int r = 0; r < 4; r++) {
                int krow = wm * 32 + fm * 16 + (lane >> 4) * 4 + r;
                int col = n0 + wn * 64 + fn * 16 + (lane & 15);
                float v = ftanh(acc[fm][fn][r] + (float)Add[ab + (long)krow * N + col]);
                ps[fn] += wsh[krow] * v;
            }
#pragma unroll
    for (int fn = 0; fn < 4; fn++)
        sred[(wm * 4 + (lane >> 4)) * 128 + wn * 64 + fn * 16 + (lane & 15)] = ps[fn];
    __syncthreads();
    if (tid < 128) {
        float s = 0.f;
#pragma unroll
        for (int j = 0; j < 8; j++) s += sred[j * 128 + tid];
        sc[(long)b * N + n0 + tid] = s;
    }
}

// ---------------- softmax over scores ----------------
__device__ __forceinline__ float wred_max(float v) {
#pragma unroll
    for (int off = 32; off > 0; off >>= 1) v = fmaxf(v, __shfl_xor(v, off, 64));
    return v;
}
__device__ __forceinline__ float wred_sum(float v) {
#pragma unroll
    for (int off = 32; off > 0; off >>= 1) v += __shfl_xor(v, off, 64);
    return v;
}

__global__ __launch_bounds__(1024)
void k_soft(const float* __restrict__ scc, const float* __restrict__ scp,
            float* __restrict__ ac, float* __restrict__ ap)
{
    __shared__ float r16[16];
    int b = blockIdx.x, tid = threadIdx.x;
    int lane = tid & 63, wid = tid >> 6;

    // drug side (512)
    float s = (tid < 512) ? scc[b * 512 + tid] : -3.4e38f;
    float m = wred_max(s);
    if (lane == 0) r16[wid] = m;
    __syncthreads();
    m = r16[0];
#pragma unroll
    for (int i = 1; i < 16; i++) m = fmaxf(m, r16[i]);
    float e = (tid < 512) ? __expf(s - m) : 0.f;
    __syncthreads();
    float t = wred_sum(e);
    if (lane == 0) r16[wid] = t;
    __syncthreads();
    float sum = 0.f;
#pragma unroll
    for (int i = 0; i < 16; i++) sum += r16[i];
    if (tid < 512) ac[b * 512 + tid] = e / sum;
    __syncthreads();

    // protein side (1024)
    float s2 = scp[b * 1024 + tid];
    float m2 = wred_max(s2);
    if (lane == 0) r16[wid] = m2;
    __syncthreads();
    m2 = r16[0];
#pragma unroll
    for (int i = 1; i < 16; i++) m2 = fmaxf(m2, r16[i]);
    float e2 = __expf(s2 - m2);
    __syncthreads();
    float t2 = wred_sum(e2);
    if (lane == 0) r16[wid] = t2;
    __syncthreads();
    float sum2 = 0.f;
#pragma unroll
    for (int i = 0; i < 16; i++) sum2 += r16[i];
    ap[b * 1024 + tid] = e2 / sum2;
}

// ---------------- weighted sums: out[b,d] = sum_l a[l] * X[b,l,d] ----------------
__global__ __launch_bounds__(512)
void k_wsum(const _Float16* __restrict__ drug_h, const _Float16* __restrict__ targ_h,
            const float* __restrict__ ac, const float* __restrict__ ap,
            float* __restrict__ out)
{
    __shared__ float ash[1024];
    __shared__ float red[32 * 128];
    int b = blockIdx.x, side = blockIdx.y;
    int L = side ? LP : LD;
    const _Float16* X = side ? targ_h : drug_h;
    const float* a = side ? ap : ac;
    float* ob = out + side * 8192 + b * 128;
    int tid = threadIdx.x;

    for (int i = tid; i < L; i += 512) ash[i] = a[(long)b * L + i];
    __syncthreads();

    int col8 = tid & 15, rg = tid >> 4;
    float accv[8];
#pragma unroll
    for (int j = 0; j < 8; j++) accv[j] = 0.f;
    const _Float16* Xb = X + (long)b * L * 128;
    for (int l = rg; l < L; l += 32) {
        half8 v = *reinterpret_cast<const half8*>(&Xb[l * 128 + col8 * 8]);
        float av = ash[l];
#pragma unroll
        for (int j = 0; j < 8; j++) accv[j] += av * (float)v[j];
    }
#pragma unroll
    for (int j = 0; j < 8; j++) red[rg * 128 + col8 * 8 + j] = accv[j];
    __syncthreads();
    if (tid < 128) {
        float s = 0.f;
#pragma unroll
        for (int g = 0; g < 32; g++) s += red[g * 128 + tid];
        ob[tid] = s;
    }
}

// ---------------- launch ----------------
extern "C" void kernel_launch(void* const* d_in, const int* in_sizes, int n_in,
                              void* d_out, int out_size, void* d_ws, size_t ws_size,
                              hipStream_t stream) {
    (void)in_sizes; (void)n_in; (void)out_size;
    const float* drug   = (const float*)d_in[0];
    const float* target = (const float*)d_in[1];
    const float* Wb     = (const float*)d_in[2];
    const float* Wx     = (const float*)d_in[3];
    const float* Wp     = (const float*)d_in[4];
    const float* whx    = (const float*)d_in[5];
    const float* whp    = (const float*)d_in[6];

    char* w = (char*)d_ws;
    size_t off = 0;
    auto takeb = [&](size_t bytes) {
        void* p = (void*)(w + off);
        off += (bytes + 255) & ~(size_t)255;
        return p;
    };
    _Float16* drug_h = (_Float16*)takeb((size_t)NB * LD * DD * 2);
    _Float16* targ_h = (_Float16*)takeb((size_t)NB * LP * DD * 2);
    _Float16* WbT_h  = (_Float16*)takeb(128 * 128 * 2);
    _Float16* Wx_h   = (_Float16*)takeb(64 * 128 * 2);
    _Float16* Wp_h   = (_Float16*)takeb(64 * 128 * 2);
    _Float16* tb_h   = (_Float16*)takeb((size_t)NB * LP * DD * 2);
    _Float16* Wxd_h  = (_Float16*)takeb((size_t)NB * KK * LD * 2);
    _Float16* Wpt_h  = (_Float16*)takeb((size_t)NB * KK * LP * 2);
    _Float16* C_h    = (_Float16*)takeb((size_t)NB * LP * LD * 2);
    _Float16* CT_h   = (_Float16*)takeb((size_t)NB * LD * LP * 2);
    float*    sc_c   = (float*)takeb((size_t)NB * LD * 4);
    float*    sc_p   = (float*)takeb((size_t)NB * LP * 4);
    float*    a_c    = (float*)takeb((size_t)NB * LD * 4);
    float*    a_p    = (float*)takeb((size_t)NB * LP * 4);

    if (off > ws_size) {                 // workspace shortfall -> sentinel (absmax ~1000)
        k_sentinel<<<1, 64, 0, stream>>>((float*)d_out);
        return;
    }

    k_conv<<<1024, 256, 0, stream>>>(drug,   drug_h, NB * LD * DD);
    k_conv<<<1024, 256, 0, stream>>>(target, targ_h, NB * LP * DD);
    k_conv<<<16, 256, 0, stream>>>(Wx, Wx_h, 64 * 128);
    k_conv<<<16, 256, 0, stream>>>(Wp, Wp_h, 64 * 128);
    k_wbt<<<64, 256, 0, stream>>>(Wb, WbT_h);

    // tb[p,d] = sum_e target[p,e] * WbT[d,e]            M=LP  N=128 Kd=128
    k_gemm<<<dim3(NB * (LP / 64)), 256, 0, stream>>>(
        targ_h, (long)LP * DD, WbT_h, 0, tb_h, (long)LP * DD, 128, 128, LP / 64, 1);
    // Wxd[k,l] = sum_d Wx[k,d] * drug[l,d]              M=64  N=LD  Kd=128
    k_gemm<<<dim3(NB * (LD / 128)), 256, 0, stream>>>(
        Wx_h, 0, drug_h, (long)LD * DD, Wxd_h, (long)KK * LD, LD, 128, 1, LD / 128);
    // Wpt[k,p] = sum_e Wp[k,e] * target[p,e]            M=64  N=LP  Kd=128
    k_gemm<<<dim3(NB * (LP / 128)), 256, 0, stream>>>(
        Wp_h, 0, targ_h, (long)LP * DD, Wpt_h, (long)KK * LP, LP, 128, 1, LP / 128);
    // C[p,l] = tanh(tb . drug^T), CT = C^T              M=LP  N=LD  Kd=128
    k_gemm_ct<<<dim3(NB * (LP / 64) * (LD / 128)), 256, 0, stream>>>(
        tb_h, (long)LP * DD, drug_h, (long)LD * DD,
        C_h, (long)LP * LD, CT_h, (long)LD * LP, LD, LP, 128, LP / 64, LD / 128);
    // sc_c[l] = sum_k whx[k]*tanh(Wxd[k,l] + sum_p Wpt[k,p]*CT[l,p])   Kd=LP
    k_gemm_score<<<dim3(NB * (LD / 128)), 256, 0, stream>>>(
        Wpt_h, (long)KK * LP, CT_h, (long)LD * LP, Wxd_h, (long)KK * LD,
        whx, sc_c, LD, LP, LD / 128);
    // sc_p[p] = sum_k whp[k]*tanh(Wpt[k,p] + sum_l Wxd[k,l]*C[p,l])    Kd=LD
    k_gemm_score<<<dim3(NB * (LP / 128)), 256, 0, stream>>>(
        Wxd_h, (long)KK * LD, C_h, (long)LP * LD, Wpt_h, (long)KK * LP,
        whp, sc_p, LP, LD, LP / 128);

    k_soft<<<NB, 1024, 0, stream>>>(sc_c, sc_p, a_c, a_p);
    k_wsum<<<dim3(NB, 2), 512, 0, stream>>>(drug_h, targ_h, a_c, a_p, (float*)d_out);
}

// Round 8
// 164.233 us; speedup vs baseline: 1.9335x; 1.0480x over previous
//
#include <hip/hip_runtime.h>
#include <hip/hip_bf16.h>
#include <math.h>

#define NB 64
#define LD 512
#define LP 1024
#define DD 128
#define KK 64

using half8 = __attribute__((ext_vector_type(8))) _Float16;
using half4 = __attribute__((ext_vector_type(4))) _Float16;
using f32x4 = __attribute__((ext_vector_type(4))) float;

// fast tanh: 1 - 2/(e^{2x}+1); inf-safe both tails
__device__ __forceinline__ float ftanh(float x) {
    float e = __expf(2.0f * x);
    return 1.0f - 2.0f / (e + 1.0f);
}

// ---------------- conversion kernels ----------------
__global__ void k_conv(const float* __restrict__ in, _Float16* __restrict__ out, int n) {
    int i = (blockIdx.x * blockDim.x + threadIdx.x) * 4;
    int stride = gridDim.x * blockDim.x * 4;
    for (; i < n; i += stride) {
        float4 v = *reinterpret_cast<const float4*>(in + i);
        half4 h;
        h.x = (_Float16)v.x; h.y = (_Float16)v.y; h.z = (_Float16)v.z; h.w = (_Float16)v.w;
        *reinterpret_cast<half4*>(out + i) = h;
    }
}

__global__ void k_wbt(const float* __restrict__ Wb, _Float16* __restrict__ WbT) {
    int t = blockIdx.x * 256 + threadIdx.x;
    int d = t >> 7, e = t & 127;
    WbT[t] = (_Float16)Wb[e * 128 + d];
}

__global__ void k_sentinel(float* out) {
    if (threadIdx.x == 0 && blockIdx.x == 0) out[0] = 1000.0f;
}

// ---------------- plain batched NT GEMM, fp16 in/out (tb, Wxd, Wpt) ----------------
__global__ __launch_bounds__(256)
void k_gemm(const _Float16* __restrict__ A, long sA,
            const _Float16* __restrict__ Bm, long sB,
            _Float16* __restrict__ Out, long sOut,
            int N, int Kd, int tilesM, int tilesN)
{
    __shared__ alignas(16) _Float16 smem[64 * 72 + 128 * 72];
    _Float16* As = smem;
    _Float16* Bs = smem + 64 * 72;

    int bid = blockIdx.x;
    int tpb = tilesM * tilesN;
    int b = bid / tpb;
    int t = bid % tpb;
    int m0 = (t / tilesN) * 64;
    int n0 = (t % tilesN) * 128;

    const _Float16* Ab = A + (long)b * sA;
    const _Float16* Bb = Bm + (long)b * sB;

    int tid = threadIdx.x;
    int lane = tid & 63;
    int wid = tid >> 6;
    int wm = wid & 1, wn = wid >> 1;

    f32x4 acc[2][4];
#pragma unroll
    for (int i = 0; i < 2; i++)
#pragma unroll
        for (int j = 0; j < 4; j++) acc[i][j] = (f32x4)(0.0f);

    for (int k0 = 0; k0 < Kd; k0 += 64) {
#pragma unroll
        for (int i = 0; i < 2; i++) {
            int c = tid + i * 256;
            int row = c >> 3, col = c & 7;
            int4 v = *reinterpret_cast<const int4*>(Ab + (long)(m0 + row) * Kd + k0 + col * 8);
            *reinterpret_cast<int4*>(&As[row * 72 + col * 8]) = v;
        }
#pragma unroll
        for (int i = 0; i < 4; i++) {
            int c = tid + i * 256;
            int row = c >> 3, col = c & 7;
            int4 v = *reinterpret_cast<const int4*>(Bb + (long)(n0 + row) * Kd + k0 + col * 8);
            *reinterpret_cast<int4*>(&Bs[row * 72 + col * 8]) = v;
        }
        __syncthreads();
#pragma unroll
        for (int kk = 0; kk < 64; kk += 32) {
            int klane = kk + 8 * (lane >> 4);
            half8 af[2], bfr[4];
#pragma unroll
            for (int fm = 0; fm < 2; fm++)
                af[fm] = *reinterpret_cast<const half8*>(&As[(wm * 32 + fm * 16 + (lane & 15)) * 72 + klane]);
#pragma unroll
            for (int fn = 0; fn < 4; fn++)
                bfr[fn] = *reinterpret_cast<const half8*>(&Bs[(wn * 64 + fn * 16 + (lane & 15)) * 72 + klane]);
#pragma unroll
            for (int fm = 0; fm < 2; fm++)
#pragma unroll
                for (int fn = 0; fn < 4; fn++)
                    acc[fm][fn] = __builtin_amdgcn_mfma_f32_16x16x32_f16(af[fm], bfr[fn], acc[fm][fn], 0, 0, 0);
        }
        __syncthreads();
    }

    long ob = (long)b * sOut;
#pragma unroll
    for (int fm = 0; fm < 2; fm++)
#pragma unroll
        for (int fn = 0; fn < 4; fn++)
#pragma unroll
            for (int r = 0; r < 4; r++) {
                int row = m0 + wm * 32 + fm * 16 + (lane >> 4) * 4 + r;
                int col = n0 + wn * 64 + fn * 16 + (lane & 15);
                Out[ob + (long)row * N + col] = (_Float16)acc[fm][fn][r];
            }
}

// ---------------- C GEMM: writes ONLY tanh(C)^T via LDS repack ----------------
// CT[b][l,p] = tanh( sum_d tb[p,d] * drug[l,d] )
__global__ __launch_bounds__(256)
void k_gemm_ct(const _Float16* __restrict__ A, long sA,      // tb [LP,DD]
               const _Float16* __restrict__ Bm, long sB,     // drug [LD,DD]
               _Float16* __restrict__ OutT, long sOutT,      // CT [LD,LP]
               int NT, int Kd, int tilesM, int tilesN)
{
    __shared__ alignas(16) _Float16 smem[64 * 72 + 128 * 72];
    _Float16* As = smem;                            // [64][72]
    _Float16* Bs = smem + 64 * 72;                  // [128][72]
    _Float16* T  = smem;                            // overlay: [128 l][72] (9216 <= 13824)

    int bid = blockIdx.x;
    int tpb = tilesM * tilesN;
    int b = bid / tpb;
    int t = bid % tpb;
    int m0 = (t / tilesN) * 64;               // p offset
    int n0 = (t % tilesN) * 128;              // l offset

    const _Float16* Ab = A + (long)b * sA;
    const _Float16* Bb = Bm + (long)b * sB;

    int tid = threadIdx.x;
    int lane = tid & 63;
    int wid = tid >> 6;
    int wm = wid & 1, wn = wid >> 1;

    f32x4 acc[2][4];
#pragma unroll
    for (int i = 0; i < 2; i++)
#pragma unroll
        for (int j = 0; j < 4; j++) acc[i][j] = (f32x4)(0.0f);

    for (int k0 = 0; k0 < Kd; k0 += 64) {
#pragma unroll
        for (int i = 0; i < 2; i++) {
            int c = tid + i * 256;
            int row = c >> 3, col = c & 7;
            int4 v = *reinterpret_cast<const int4*>(Ab + (long)(m0 + row) * Kd + k0 + col * 8);
            *reinterpret_cast<int4*>(&As[row * 72 + col * 8]) = v;
        }
#pragma unroll
        for (int i = 0; i < 4; i++) {
            int c = tid + i * 256;
            int row = c >> 3, col = c & 7;
            int4 v = *reinterpret_cast<const int4*>(Bb + (long)(n0 + row) * Kd + k0 + col * 8);
            *reinterpret_cast<int4*>(&Bs[row * 72 + col * 8]) = v;
        }
        __syncthreads();
#pragma unroll
        for (int kk = 0; kk < 64; kk += 32) {
            int klane = kk + 8 * (lane >> 4);
            half8 af[2], bfr[4];
#pragma unroll
            for (int fm = 0; fm < 2; fm++)
                af[fm] = *reinterpret_cast<const half8*>(&As[(wm * 32 + fm * 16 + (lane & 15)) * 72 + klane]);
#pragma unroll
            for (int fn = 0; fn < 4; fn++)
                bfr[fn] = *reinterpret_cast<const half8*>(&Bs[(wn * 64 + fn * 16 + (lane & 15)) * 72 + klane]);
#pragma unroll
            for (int fm = 0; fm < 2; fm++)
#pragma unroll
                for (int fn = 0; fn < 4; fn++)
                    acc[fm][fn] = __builtin_amdgcn_mfma_f32_16x16x32_f16(af[fm], bfr[fn], acc[fm][fn], 0, 0, 0);
        }
        __syncthreads();
    }

    // scatter tanh'd acc into transposed LDS overlay
#pragma unroll
    for (int fm = 0; fm < 2; fm++)
#pragma unroll
        for (int fn = 0; fn < 4; fn++)
#pragma unroll
            for (int r = 0; r < 4; r++) {
                int lp = wm * 32 + fm * 16 + (lane >> 4) * 4 + r;   // local p
                int ll = wn * 64 + fn * 16 + (lane & 15);           // local l
                T[ll * 72 + lp] = (_Float16)ftanh(acc[fm][fn][r]);
            }
    __syncthreads();

    long obT = (long)b * sOutT;
#pragma unroll
    for (int i = 0; i < 4; i++) {
        int c = tid + i * 256;                // 1024 int4 = 128 rows x 8
        int rowT = c >> 3, cp = (c & 7) * 8;
        int4 v = *reinterpret_cast<const int4*>(&T[rowT * 72 + cp]);
        *reinterpret_cast<int4*>(&OutT[obT + (long)(n0 + rowT) * NT + m0 + cp]) = v;
    }
}

// ---------------- H GEMM + fused score: sc[b,n] = sum_k w[k]*tanh(acc+Add) ----------------
// BM=64 (= all K rows), BN=128. No H output.
// TRANSB: stage B transposed from CT (B_logical[n][K] = CT[K][n], row stride bRowStride).
template<bool TRANSB>
__global__ __launch_bounds__(256)
void k_gemm_score(const _Float16* __restrict__ A, long sA,
                  const _Float16* __restrict__ Bm, long sB,
                  const _Float16* __restrict__ Add, long sAdd,
                  const float* __restrict__ wv,
                  float* __restrict__ sc,
                  int N, int Kd, int bRowStride, int tilesN)
{
    __shared__ alignas(16) _Float16 smem[64 * 72 + 128 * 72];
    __shared__ float sred[8 * 128];
    __shared__ float wsh[64];
    _Float16* As = smem;
    _Float16* Bs = smem + 64 * 72;

    int bid = blockIdx.x;
    int b = bid / tilesN;
    int n0 = (bid % tilesN) * 128;

    const _Float16* Ab = A + (long)b * sA;
    const _Float16* Bb = Bm + (long)b * sB;

    int tid = threadIdx.x;
    int lane = tid & 63;
    int wid = tid >> 6;
    int wm = wid & 1, wn = wid >> 1;

    if (tid < 64) wsh[tid] = wv[tid];       // synced by first loop barrier

    f32x4 acc[2][4];
#pragma unroll
    for (int i = 0; i < 2; i++)
#pragma unroll
        for (int j = 0; j < 4; j++) acc[i][j] = (f32x4)(0.0f);

    for (int k0 = 0; k0 < Kd; k0 += 64) {
#pragma unroll
        for (int i = 0; i < 2; i++) {
            int c = tid + i * 256;
            int row = c >> 3, col = c & 7;
            int4 v = *reinterpret_cast<const int4*>(Ab + (long)row * Kd + k0 + col * 8);
            *reinterpret_cast<int4*>(&As[row * 72 + col * 8]) = v;
        }
        if constexpr (TRANSB) {
            // B-tile [128 n][64 K] from CT rows: CT[k0+l][n0+p8..p8+7]
#pragma unroll
            for (int i = 0; i < 4; i++) {
                int c = tid + i * 256;
                int l = c & 63, p8 = (c >> 6) * 8;
                int4 v = *reinterpret_cast<const int4*>(Bb + (long)(k0 + l) * bRowStride + n0 + p8);
                half8 hv = *reinterpret_cast<const half8*>(&v);
#pragma unroll
                for (int j = 0; j < 8; j++)
                    Bs[(p8 + j) * 72 + l] = hv[j];     // lanes: distinct l, same p-row -> 2-way free
            }
        } else {
#pragma unroll
            for (int i = 0; i < 4; i++) {
                int c = tid + i * 256;
                int row = c >> 3, col = c & 7;
                int4 v = *reinterpret_cast<const int4*>(Bb + (long)(n0 + row) * bRowStride + k0 + col * 8);
                *reinterpret_cast<int4*>(&Bs[row * 72 + col * 8]) = v;
            }
        }
        __syncthreads();
#pragma unroll
        for (int kk = 0; kk < 64; kk += 32) {
            int klane = kk + 8 * (lane >> 4);
            half8 af[2], bfr[4];
#pragma unroll
            for (int fm = 0; fm < 2; fm++)
                af[fm] = *reinterpret_cast<const half8*>(&As[(wm * 32 + fm * 16 + (lane & 15)) * 72 + klane]);
#pragma unroll
            for (int fn = 0; fn < 4; fn++)
                bfr[fn] = *reinterpret_cast<const half8*>(&Bs[(wn * 64 + fn * 16 + (lane & 15)) * 72 + klane]);
#pragma unroll
            for (int fm = 0; fm < 2; fm++)
#pragma unroll
                for (int fn = 0; fn < 4; fn++)
                    acc[fm][fn] = __builtin_amdgcn_mfma_f32_16x16x32_f16(af[fm], bfr[fn], acc[fm][fn], 0, 0, 0);
        }
        __syncthreads();
    }

    long ab = (long)b * sAdd;
    float ps[4] = {0.f, 0.f, 0.f, 0.f};
#pragma unroll
    for (int fm = 0; fm < 2; fm++)
#pragma unroll
        for (int fn = 0; fn < 4; fn++)
#pragma unroll
            for (int r = 0; r < 4; r++) {
                int krow = wm * 32 + fm * 16 + (lane >> 4) * 4 + r;
                int col = n0 + wn * 64 + fn * 16 + (lane & 15);
                float v = ftanh(acc[fm][fn][r] + (float)Add[ab + (long)krow * N + col]);
                ps[fn] += wsh[krow] * v;
            }
#pragma unroll
    for (int fn = 0; fn < 4; fn++)
        sred[(wm * 4 + (lane >> 4)) * 128 + wn * 64 + fn * 16 + (lane & 15)] = ps[fn];
    __syncthreads();
    if (tid < 128) {
        float s = 0.f;
#pragma unroll
        for (int j = 0; j < 8; j++) s += sred[j * 128 + tid];
        sc[(long)b * N + n0 + tid] = s;
    }
}

// ---------------- softmax over scores ----------------
__device__ __forceinline__ float wred_max(float v) {
#pragma unroll
    for (int off = 32; off > 0; off >>= 1) v = fmaxf(v, __shfl_xor(v, off, 64));
    return v;
}
__device__ __forceinline__ float wred_sum(float v) {
#pragma unroll
    for (int off = 32; off > 0; off >>= 1) v += __shfl_xor(v, off, 64);
    return v;
}

__global__ __launch_bounds__(1024)
void k_soft(const float* __restrict__ scc, const float* __restrict__ scp,
            float* __restrict__ ac, float* __restrict__ ap)
{
    __shared__ float r16[16];
    int b = blockIdx.x, tid = threadIdx.x;
    int lane = tid & 63, wid = tid >> 6;

    float s = (tid < 512) ? scc[b * 512 + tid] : -3.4e38f;
    float m = wred_max(s);
    if (lane == 0) r16[wid] = m;
    __syncthreads();
    m = r16[0];
#pragma unroll
    for (int i = 1; i < 16; i++) m = fmaxf(m, r16[i]);
    float e = (tid < 512) ? __expf(s - m) : 0.f;
    __syncthreads();
    float t = wred_sum(e);
    if (lane == 0) r16[wid] = t;
    __syncthreads();
    float sum = 0.f;
#pragma unroll
    for (int i = 0; i < 16; i++) sum += r16[i];
    if (tid < 512) ac[b * 512 + tid] = e / sum;
    __syncthreads();

    float s2 = scp[b * 1024 + tid];
    float m2 = wred_max(s2);
    if (lane == 0) r16[wid] = m2;
    __syncthreads();
    m2 = r16[0];
#pragma unroll
    for (int i = 1; i < 16; i++) m2 = fmaxf(m2, r16[i]);
    float e2 = __expf(s2 - m2);
    __syncthreads();
    float t2 = wred_sum(e2);
    if (lane == 0) r16[wid] = t2;
    __syncthreads();
    float sum2 = 0.f;
#pragma unroll
    for (int i = 0; i < 16; i++) sum2 += r16[i];
    ap[b * 1024 + tid] = e2 / sum2;
}

// ---------------- weighted sums: out[b,d] = sum_l a[l] * X[b,l,d] ----------------
__global__ __launch_bounds__(512)
void k_wsum(const _Float16* __restrict__ drug_h, const _Float16* __restrict__ targ_h,
            const float* __restrict__ ac, const float* __restrict__ ap,
            float* __restrict__ out)
{
    __shared__ float ash[1024];
    __shared__ float red[32 * 128];
    int b = blockIdx.x, side = blockIdx.y;
    int L = side ? LP : LD;
    const _Float16* X = side ? targ_h : drug_h;
    const float* a = side ? ap : ac;
    float* ob = out + side * 8192 + b * 128;
    int tid = threadIdx.x;

    for (int i = tid; i < L; i += 512) ash[i] = a[(long)b * L + i];
    __syncthreads();

    int col8 = tid & 15, rg = tid >> 4;
    float accv[8];
#pragma unroll
    for (int j = 0; j < 8; j++) accv[j] = 0.f;
    const _Float16* Xb = X + (long)b * L * 128;
    for (int l = rg; l < L; l += 32) {
        half8 v = *reinterpret_cast<const half8*>(&Xb[l * 128 + col8 * 8]);
        float av = ash[l];
#pragma unroll
        for (int j = 0; j < 8; j++) accv[j] += av * (float)v[j];
    }
#pragma unroll
    for (int j = 0; j < 8; j++) red[rg * 128 + col8 * 8 + j] = accv[j];
    __syncthreads();
    if (tid < 128) {
        float s = 0.f;
#pragma unroll
        for (int g = 0; g < 32; g++) s += red[g * 128 + tid];
        ob[tid] = s;
    }
}

// ---------------- launch ----------------
extern "C" void kernel_launch(void* const* d_in, const int* in_sizes, int n_in,
                              void* d_out, int out_size, void* d_ws, size_t ws_size,
                              hipStream_t stream) {
    (void)in_sizes; (void)n_in; (void)out_size;
    const float* drug   = (const float*)d_in[0];
    const float* target = (const float*)d_in[1];
    const float* Wb     = (const float*)d_in[2];
    const float* Wx     = (const float*)d_in[3];
    const float* Wp     = (const float*)d_in[4];
    const float* whx    = (const float*)d_in[5];
    const float* whp    = (const float*)d_in[6];

    char* w = (char*)d_ws;
    size_t off = 0;
    auto takeb = [&](size_t bytes) {
        void* p = (void*)(w + off);
        off += (bytes + 255) & ~(size_t)255;
        return p;
    };
    _Float16* drug_h = (_Float16*)takeb((size_t)NB * LD * DD * 2);
    _Float16* targ_h = (_Float16*)takeb((size_t)NB * LP * DD * 2);
    _Float16* WbT_h  = (_Float16*)takeb(128 * 128 * 2);
    _Float16* Wx_h   = (_Float16*)takeb(64 * 128 * 2);
    _Float16* Wp_h   = (_Float16*)takeb(64 * 128 * 2);
    _Float16* tb_h   = (_Float16*)takeb((size_t)NB * LP * DD * 2);
    _Float16* Wxd_h  = (_Float16*)takeb((size_t)NB * KK * LD * 2);
    _Float16* Wpt_h  = (_Float16*)takeb((size_t)NB * KK * LP * 2);
    _Float16* CT_h   = (_Float16*)takeb((size_t)NB * LD * LP * 2);
    float*    sc_c   = (float*)takeb((size_t)NB * LD * 4);
    float*    sc_p   = (float*)takeb((size_t)NB * LP * 4);
    float*    a_c    = (float*)takeb((size_t)NB * LD * 4);
    float*    a_p    = (float*)takeb((size_t)NB * LP * 4);

    if (off > ws_size) {                 // workspace shortfall -> sentinel (absmax ~1000)
        k_sentinel<<<1, 64, 0, stream>>>((float*)d_out);
        return;
    }

    k_conv<<<1024, 256, 0, stream>>>(drug,   drug_h, NB * LD * DD);
    k_conv<<<1024, 256, 0, stream>>>(target, targ_h, NB * LP * DD);
    k_conv<<<16, 256, 0, stream>>>(Wx, Wx_h, 64 * 128);
    k_conv<<<16, 256, 0, stream>>>(Wp, Wp_h, 64 * 128);
    k_wbt<<<64, 256, 0, stream>>>(Wb, WbT_h);

    // tb[p,d] = sum_e target[p,e] * WbT[d,e]            M=LP  N=128 Kd=128
    k_gemm<<<dim3(NB * (LP / 64)), 256, 0, stream>>>(
        targ_h, (long)LP * DD, WbT_h, 0, tb_h, (long)LP * DD, 128, 128, LP / 64, 1);
    // Wxd[k,l] = sum_d Wx[k,d] * drug[l,d]              M=64  N=LD  Kd=128
    k_gemm<<<dim3(NB * (LD / 128)), 256, 0, stream>>>(
        Wx_h, 0, drug_h, (long)LD * DD, Wxd_h, (long)KK * LD, LD, 128, 1, LD / 128);
    // Wpt[k,p] = sum_e Wp[k,e] * target[p,e]            M=64  N=LP  Kd=128
    k_gemm<<<dim3(NB * (LP / 128)), 256, 0, stream>>>(
        Wp_h, 0, targ_h, (long)LP * DD, Wpt_h, (long)KK * LP, LP, 128, 1, LP / 128);
    // CT[l,p] = tanh( sum_d tb[p,d]*drug[l,d] )  (ONLY transposed orientation)
    k_gemm_ct<<<dim3(NB * (LP / 64) * (LD / 128)), 256, 0, stream>>>(
        tb_h, (long)LP * DD, drug_h, (long)LD * DD,
        CT_h, (long)LD * LP, LP, 128, LP / 64, LD / 128);
    // sc_c[l] = sum_k whx[k]*tanh(Wxd[k,l] + sum_p Wpt[k,p]*CT[l,p])   Kd=LP, B=CT rows
    k_gemm_score<false><<<dim3(NB * (LD / 128)), 256, 0, stream>>>(
        Wpt_h, (long)KK * LP, CT_h, (long)LD * LP, Wxd_h, (long)KK * LD,
        whx, sc_c, LD, LP, LP, LD / 128);
    // sc_p[p] = sum_k whp[k]*tanh(Wpt[k,p] + sum_l Wxd[k,l]*C[p,l])    Kd=LD, B=CT transposed-stage
    k_gemm_score<true><<<dim3(NB * (LP / 128)), 256, 0, stream>>>(
        Wxd_h, (long)KK * LD, CT_h, (long)LD * LP, Wpt_h, (long)KK * LP,
        whp, sc_p, LP, LD, LP, LP / 128);

    k_soft<<<NB, 1024, 0, stream>>>(sc_c, sc_p, a_c, a_p);
    k_wsum<<<dim3(NB, 2), 512, 0, stream>>>(drug_h, targ_h, a_c, a_p, (float*)d_out);
}

// Round 9
// 144.854 us; speedup vs baseline: 2.1921x; 1.1338x over previous
//
#include <hip/hip_runtime.h>
#include <hip/hip_bf16.h>
#include <math.h>

#define NB 64
#define LD 512
#define LP 1024
#define DD 128
#define KK 64

using half8 = __attribute__((ext_vector_type(8))) _Float16;
using half4 = __attribute__((ext_vector_type(4))) _Float16;
using f32x4 = __attribute__((ext_vector_type(4))) float;

// fast tanh: 1 - 2/(e^{2x}+1); inf-safe both tails
__device__ __forceinline__ float ftanh(float x) {
    float e = __expf(2.0f * x);
    return 1.0f - 2.0f / (e + 1.0f);
}

// ---------------- conversion kernels ----------------
__global__ void k_conv(const float* __restrict__ in, _Float16* __restrict__ out, int n) {
    int i = (blockIdx.x * blockDim.x + threadIdx.x) * 4;
    int stride = gridDim.x * blockDim.x * 4;
    for (; i < n; i += stride) {
        float4 v = *reinterpret_cast<const float4*>(in + i);
        half4 h;
        h.x = (_Float16)v.x; h.y = (_Float16)v.y; h.z = (_Float16)v.z; h.w = (_Float16)v.w;
        *reinterpret_cast<half4*>(out + i) = h;
    }
}

__global__ void k_wbt(const float* __restrict__ Wb, _Float16* __restrict__ WbT) {
    int t = blockIdx.x * 256 + threadIdx.x;
    int d = t >> 7, e = t & 127;
    WbT[t] = (_Float16)Wb[e * 128 + d];
}

__global__ void k_sentinel(float* out) {
    if (threadIdx.x == 0 && blockIdx.x == 0) out[0] = 1000.0f;
}

// ---------------- plain batched NT GEMM, fp16 in/out (tb, Wxd, Wpt) ----------------
__global__ __launch_bounds__(256)
void k_gemm(const _Float16* __restrict__ A, long sA,
            const _Float16* __restrict__ Bm, long sB,
            _Float16* __restrict__ Out, long sOut,
            int N, int Kd, int tilesM, int tilesN)
{
    __shared__ alignas(16) _Float16 smem[64 * 72 + 128 * 72];
    _Float16* As = smem;
    _Float16* Bs = smem + 64 * 72;

    int bid = blockIdx.x;
    int tpb = tilesM * tilesN;
    int b = bid / tpb;
    int t = bid % tpb;
    int m0 = (t / tilesN) * 64;
    int n0 = (t % tilesN) * 128;

    const _Float16* Ab = A + (long)b * sA;
    const _Float16* Bb = Bm + (long)b * sB;

    int tid = threadIdx.x;
    int lane = tid & 63;
    int wid = tid >> 6;
    int wm = wid & 1, wn = wid >> 1;

    f32x4 acc[2][4];
#pragma unroll
    for (int i = 0; i < 2; i++)
#pragma unroll
        for (int j = 0; j < 4; j++) acc[i][j] = (f32x4)(0.0f);

    for (int k0 = 0; k0 < Kd; k0 += 64) {
#pragma unroll
        for (int i = 0; i < 2; i++) {
            int c = tid + i * 256;
            int row = c >> 3, col = c & 7;
            int4 v = *reinterpret_cast<const int4*>(Ab + (long)(m0 + row) * Kd + k0 + col * 8);
            *reinterpret_cast<int4*>(&As[row * 72 + col * 8]) = v;
        }
#pragma unroll
        for (int i = 0; i < 4; i++) {
            int c = tid + i * 256;
            int row = c >> 3, col = c & 7;
            int4 v = *reinterpret_cast<const int4*>(Bb + (long)(n0 + row) * Kd + k0 + col * 8);
            *reinterpret_cast<int4*>(&Bs[row * 72 + col * 8]) = v;
        }
        __syncthreads();
#pragma unroll
        for (int kk = 0; kk < 64; kk += 32) {
            int klane = kk + 8 * (lane >> 4);
            half8 af[2], bfr[4];
#pragma unroll
            for (int fm = 0; fm < 2; fm++)
                af[fm] = *reinterpret_cast<const half8*>(&As[(wm * 32 + fm * 16 + (lane & 15)) * 72 + klane]);
#pragma unroll
            for (int fn = 0; fn < 4; fn++)
                bfr[fn] = *reinterpret_cast<const half8*>(&Bs[(wn * 64 + fn * 16 + (lane & 15)) * 72 + klane]);
#pragma unroll
            for (int fm = 0; fm < 2; fm++)
#pragma unroll
                for (int fn = 0; fn < 4; fn++)
                    acc[fm][fn] = __builtin_amdgcn_mfma_f32_16x16x32_f16(af[fm], bfr[fn], acc[fm][fn], 0, 0, 0);
        }
        __syncthreads();
    }

    long ob = (long)b * sOut;
#pragma unroll
    for (int fm = 0; fm < 2; fm++)
#pragma unroll
        for (int fn = 0; fn < 4; fn++)
#pragma unroll
            for (int r = 0; r < 4; r++) {
                int row = m0 + wm * 32 + fm * 16 + (lane >> 4) * 4 + r;
                int col = n0 + wn * 64 + fn * 16 + (lane & 15);
                Out[ob + (long)row * N + col] = (_Float16)acc[fm][fn][r];
            }
}

// ---------------- fused C + H + score kernel (both sides in ONE dispatch) ----------------
// side C (bid < 512):  sc_c[b, n0+j] = sum_k whx[k]*tanh(Wxd[k,n0+j] + sum_p Wpt[k,p]*C[p,n0+j])
//   with C[p,l] = tanh(sum_d tb[p,d]*drug[l,d]); resident rows = drug l's, stream = tb p's.
// side P (bid >= 512): sc_p[b, n0+j] = sum_k whp[k]*tanh(Wpt[k,n0+j] + sum_l Wxd[k,l]*C[n0+j,l])
//   resident rows = tb p's, stream = drug l's.
// Per step: GEMM1 (64res x 64strm x 128d) -> tanh -> Ct LDS -> GEMM2 (64k x 64res x 64strm) accum.
__global__ __launch_bounds__(256)
void k_score_fused(const _Float16* __restrict__ drug_h, const _Float16* __restrict__ tb_h,
                   const _Float16* __restrict__ Wxd_h, const _Float16* __restrict__ Wpt_h,
                   const float* __restrict__ whx, const float* __restrict__ whp,
                   float* __restrict__ sc_c, float* __restrict__ sc_p)
{
    __shared__ alignas(16) _Float16 Rs[64 * 136];   // resident [64][128+8]
    __shared__ alignas(16) _Float16 Ss[64 * 136];   // streamed [64][128+8]
    __shared__ alignas(16) _Float16 Ws[64 * 72];    // W slice  [64k][64+8]
    __shared__ alignas(16) _Float16 Cts[64 * 72];   // C tile   [64res][64strm+8]
    __shared__ float sred[8 * 64];
    __shared__ float wsh[64];

    int bid = blockIdx.x;
    int tid = threadIdx.x;
    int lane = tid & 63;
    int wid = tid >> 6;
    int wm = wid & 1, wn = wid >> 1;

    int b, n0, nsteps, Ntot, sW;
    const _Float16 *R, *S, *W, *Add;
    const float* wv;
    float* out;
    if (bid < 512) {
        b = bid >> 3; n0 = (bid & 7) * 64;
        R = drug_h + (long)b * (LD * DD);
        S = tb_h   + (long)b * (LP * DD);
        W = Wpt_h  + (long)b * (KK * LP);  sW = LP;
        Add = Wxd_h + (long)b * (KK * LD); Ntot = LD;
        nsteps = LP / 64; wv = whx; out = sc_c + (long)b * LD;
    } else {
        int q = bid - 512;
        b = q >> 4; n0 = (q & 15) * 64;
        R = tb_h   + (long)b * (LP * DD);
        S = drug_h + (long)b * (LD * DD);
        W = Wxd_h  + (long)b * (KK * LD);  sW = LD;
        Add = Wpt_h + (long)b * (KK * LP); Ntot = LP;
        nsteps = LD / 64; wv = whp; out = sc_p + (long)b * LP;
    }

    // stage resident tile [64][128] + w
#pragma unroll
    for (int i = 0; i < 4; i++) {
        int c = tid + i * 256;
        int row = c >> 4, col8 = (c & 15) * 8;
        int4 v = *reinterpret_cast<const int4*>(R + (long)(n0 + row) * DD + col8);
        *reinterpret_cast<int4*>(&Rs[row * 136 + col8]) = v;
    }
    if (tid < 64) wsh[tid] = wv[tid];

    f32x4 acc2[2][2];
#pragma unroll
    for (int i = 0; i < 2; i++)
#pragma unroll
        for (int j = 0; j < 2; j++) acc2[i][j] = (f32x4)(0.0f);

    for (int s = 0; s < nsteps; s++) {
        __syncthreads();                  // prev GEMM2 done (iter 0: nothing)
        // stage stream tile [64][128]
#pragma unroll
        for (int i = 0; i < 4; i++) {
            int c = tid + i * 256;
            int row = c >> 4, col8 = (c & 15) * 8;
            int4 v = *reinterpret_cast<const int4*>(S + (long)(s * 64 + row) * DD + col8);
            *reinterpret_cast<int4*>(&Ss[row * 136 + col8]) = v;
        }
        // stage W slice [64][64]
#pragma unroll
        for (int i = 0; i < 2; i++) {
            int c = tid + i * 256;
            int row = c >> 3, col8 = (c & 7) * 8;
            int4 v = *reinterpret_cast<const int4*>(W + (long)row * sW + s * 64 + col8);
            *reinterpret_cast<int4*>(&Ws[row * 72 + col8]) = v;
        }
        __syncthreads();                  // staging complete (also covers Rs/wsh at s=0)

        // GEMM1: acc1[res, strm] = sum_d Rs[res,d]*Ss[strm,d]
        f32x4 a1[2][2];
#pragma unroll
        for (int i = 0; i < 2; i++)
#pragma unroll
            for (int j = 0; j < 2; j++) a1[i][j] = (f32x4)(0.0f);
#pragma unroll
        for (int kk = 0; kk < 4; kk++) {
            int klane = kk * 32 + 8 * (lane >> 4);
            half8 af[2], bf[2];
#pragma unroll
            for (int fm = 0; fm < 2; fm++)
                af[fm] = *reinterpret_cast<const half8*>(&Rs[(wm * 32 + fm * 16 + (lane & 15)) * 136 + klane]);
#pragma unroll
            for (int fn = 0; fn < 2; fn++)
                bf[fn] = *reinterpret_cast<const half8*>(&Ss[(wn * 32 + fn * 16 + (lane & 15)) * 136 + klane]);
#pragma unroll
            for (int fm = 0; fm < 2; fm++)
#pragma unroll
                for (int fn = 0; fn < 2; fn++)
                    a1[fm][fn] = __builtin_amdgcn_mfma_f32_16x16x32_f16(af[fm], bf[fn], a1[fm][fn], 0, 0, 0);
        }
        // tanh -> Ct [res][strm]  (row-major == GEMM2 B operand layout)
#pragma unroll
        for (int fm = 0; fm < 2; fm++)
#pragma unroll
            for (int fn = 0; fn < 2; fn++)
#pragma unroll
                for (int r = 0; r < 4; r++) {
                    int res  = wm * 32 + fm * 16 + (lane >> 4) * 4 + r;
                    int strm = wn * 32 + fn * 16 + (lane & 15);
                    Cts[res * 72 + strm] = (_Float16)ftanh(a1[fm][fn][r]);
                }
        __syncthreads();                  // Ct complete

        // GEMM2: acc2[k, res] += sum_strm Ws[k,strm]*Cts[res,strm]
#pragma unroll
        for (int kk = 0; kk < 2; kk++) {
            int klane = kk * 32 + 8 * (lane >> 4);
            half8 af[2], bf[2];
#pragma unroll
            for (int fm = 0; fm < 2; fm++)
                af[fm] = *reinterpret_cast<const half8*>(&Ws[(wm * 32 + fm * 16 + (lane & 15)) * 72 + klane]);
#pragma unroll
            for (int fn = 0; fn < 2; fn++)
                bf[fn] = *reinterpret_cast<const half8*>(&Cts[(wn * 32 + fn * 16 + (lane & 15)) * 72 + klane]);
#pragma unroll
            for (int fm = 0; fm < 2; fm++)
#pragma unroll
                for (int fn = 0; fn < 2; fn++)
                    acc2[fm][fn] = __builtin_amdgcn_mfma_f32_16x16x32_f16(af[fm], bf[fn], acc2[fm][fn], 0, 0, 0);
        }
    }

    // epilogue: + Add, tanh, dot w, block reduce over k
    float ps[2] = {0.f, 0.f};
#pragma unroll
    for (int fm = 0; fm < 2; fm++)
#pragma unroll
        for (int fn = 0; fn < 2; fn++)
#pragma unroll
            for (int r = 0; r < 4; r++) {
                int k   = wm * 32 + fm * 16 + (lane >> 4) * 4 + r;
                int col = wn * 32 + fn * 16 + (lane & 15);
                float v = ftanh(acc2[fm][fn][r] + (float)Add[(long)k * Ntot + n0 + col]);
                ps[fn] += wsh[k] * v;
            }
#pragma unroll
    for (int fn = 0; fn < 2; fn++)
        sred[(wm * 4 + (lane >> 4)) * 64 + wn * 32 + fn * 16 + (lane & 15)] = ps[fn];
    __syncthreads();
    if (tid < 64) {
        float sacc = 0.f;
#pragma unroll
        for (int j = 0; j < 8; j++) sacc += sred[j * 64 + tid];
        out[n0 + tid] = sacc;
    }
}

// ---------------- softmax over scores ----------------
__device__ __forceinline__ float wred_max(float v) {
#pragma unroll
    for (int off = 32; off > 0; off >>= 1) v = fmaxf(v, __shfl_xor(v, off, 64));
    return v;
}
__device__ __forceinline__ float wred_sum(float v) {
#pragma unroll
    for (int off = 32; off > 0; off >>= 1) v += __shfl_xor(v, off, 64);
    return v;
}

__global__ __launch_bounds__(1024)
void k_soft(const float* __restrict__ scc, const float* __restrict__ scp,
            float* __restrict__ ac, float* __restrict__ ap)
{
    __shared__ float r16[16];
    int b = blockIdx.x, tid = threadIdx.x;
    int lane = tid & 63, wid = tid >> 6;

    float s = (tid < 512) ? scc[b * 512 + tid] : -3.4e38f;
    float m = wred_max(s);
    if (lane == 0) r16[wid] = m;
    __syncthreads();
    m = r16[0];
#pragma unroll
    for (int i = 1; i < 16; i++) m = fmaxf(m, r16[i]);
    float e = (tid < 512) ? __expf(s - m) : 0.f;
    __syncthreads();
    float t = wred_sum(e);
    if (lane == 0) r16[wid] = t;
    __syncthreads();
    float sum = 0.f;
#pragma unroll
    for (int i = 0; i < 16; i++) sum += r16[i];
    if (tid < 512) ac[b * 512 + tid] = e / sum;
    __syncthreads();

    float s2 = scp[b * 1024 + tid];
    float m2 = wred_max(s2);
    if (lane == 0) r16[wid] = m2;
    __syncthreads();
    m2 = r16[0];
#pragma unroll
    for (int i = 1; i < 16; i++) m2 = fmaxf(m2, r16[i]);
    float e2 = __expf(s2 - m2);
    __syncthreads();
    float t2 = wred_sum(e2);
    if (lane == 0) r16[wid] = t2;
    __syncthreads();
    float sum2 = 0.f;
#pragma unroll
    for (int i = 0; i < 16; i++) sum2 += r16[i];
    ap[b * 1024 + tid] = e2 / sum2;
}

// ---------------- weighted sums: out[b,d] = sum_l a[l] * X[b,l,d] ----------------
__global__ __launch_bounds__(512)
void k_wsum(const _Float16* __restrict__ drug_h, const _Float16* __restrict__ targ_h,
            const float* __restrict__ ac, const float* __restrict__ ap,
            float* __restrict__ out)
{
    __shared__ float ash[1024];
    __shared__ float red[32 * 128];
    int b = blockIdx.x, side = blockIdx.y;
    int L = side ? LP : LD;
    const _Float16* X = side ? targ_h : drug_h;
    const float* a = side ? ap : ac;
    float* ob = out + side * 8192 + b * 128;
    int tid = threadIdx.x;

    for (int i = tid; i < L; i += 512) ash[i] = a[(long)b * L + i];
    __syncthreads();

    int col8 = tid & 15, rg = tid >> 4;
    float accv[8];
#pragma unroll
    for (int j = 0; j < 8; j++) accv[j] = 0.f;
    const _Float16* Xb = X + (long)b * L * 128;
    for (int l = rg; l < L; l += 32) {
        half8 v = *reinterpret_cast<const half8*>(&Xb[l * 128 + col8 * 8]);
        float av = ash[l];
#pragma unroll
        for (int j = 0; j < 8; j++) accv[j] += av * (float)v[j];
    }
#pragma unroll
    for (int j = 0; j < 8; j++) red[rg * 128 + col8 * 8 + j] = accv[j];
    __syncthreads();
    if (tid < 128) {
        float s = 0.f;
#pragma unroll
        for (int g = 0; g < 32; g++) s += red[g * 128 + tid];
        ob[tid] = s;
    }
}

// ---------------- launch ----------------
extern "C" void kernel_launch(void* const* d_in, const int* in_sizes, int n_in,
                              void* d_out, int out_size, void* d_ws, size_t ws_size,
                              hipStream_t stream) {
    (void)in_sizes; (void)n_in; (void)out_size;
    const float* drug   = (const float*)d_in[0];
    const float* target = (const float*)d_in[1];
    const float* Wb     = (const float*)d_in[2];
    const float* Wx     = (const float*)d_in[3];
    const float* Wp     = (const float*)d_in[4];
    const float* whx    = (const float*)d_in[5];
    const float* whp    = (const float*)d_in[6];

    char* w = (char*)d_ws;
    size_t off = 0;
    auto takeb = [&](size_t bytes) {
        void* p = (void*)(w + off);
        off += (bytes + 255) & ~(size_t)255;
        return p;
    };
    _Float16* drug_h = (_Float16*)takeb((size_t)NB * LD * DD * 2);
    _Float16* targ_h = (_Float16*)takeb((size_t)NB * LP * DD * 2);
    _Float16* WbT_h  = (_Float16*)takeb(128 * 128 * 2);
    _Float16* Wx_h   = (_Float16*)takeb(64 * 128 * 2);
    _Float16* Wp_h   = (_Float16*)takeb(64 * 128 * 2);
    _Float16* tb_h   = (_Float16*)takeb((size_t)NB * LP * DD * 2);
    _Float16* Wxd_h  = (_Float16*)takeb((size_t)NB * KK * LD * 2);
    _Float16* Wpt_h  = (_Float16*)takeb((size_t)NB * KK * LP * 2);
    float*    sc_c   = (float*)takeb((size_t)NB * LD * 4);
    float*    sc_p   = (float*)takeb((size_t)NB * LP * 4);
    float*    a_c    = (float*)takeb((size_t)NB * LD * 4);
    float*    a_p    = (float*)takeb((size_t)NB * LP * 4);

    if (off > ws_size) {                 // workspace shortfall -> sentinel (absmax ~1000)
        k_sentinel<<<1, 64, 0, stream>>>((float*)d_out);
        return;
    }

    k_conv<<<1024, 256, 0, stream>>>(drug,   drug_h, NB * LD * DD);
    k_conv<<<1024, 256, 0, stream>>>(target, targ_h, NB * LP * DD);
    k_conv<<<16, 256, 0, stream>>>(Wx, Wx_h, 64 * 128);
    k_conv<<<16, 256, 0, stream>>>(Wp, Wp_h, 64 * 128);
    k_wbt<<<64, 256, 0, stream>>>(Wb, WbT_h);

    // tb[p,d] = sum_e target[p,e] * WbT[d,e]            M=LP  N=128 Kd=128
    k_gemm<<<dim3(NB * (LP / 64)), 256, 0, stream>>>(
        targ_h, (long)LP * DD, WbT_h, 0, tb_h, (long)LP * DD, 128, 128, LP / 64, 1);
    // Wxd[k,l] = sum_d Wx[k,d] * drug[l,d]              M=64  N=LD  Kd=128
    k_gemm<<<dim3(NB * (LD / 128)), 256, 0, stream>>>(
        Wx_h, 0, drug_h, (long)LD * DD, Wxd_h, (long)KK * LD, LD, 128, 1, LD / 128);
    // Wpt[k,p] = sum_e Wp[k,e] * target[p,e]            M=64  N=LP  Kd=128
    k_gemm<<<dim3(NB * (LP / 128)), 256, 0, stream>>>(
        Wp_h, 0, targ_h, (long)LP * DD, Wpt_h, (long)KK * LP, LP, 128, 1, LP / 128);

    // fused: C recomputed per side in-LDS; scores out directly
    k_score_fused<<<dim3(512 + 1024), 256, 0, stream>>>(
        drug_h, tb_h, Wxd_h, Wpt_h, whx, whp, sc_c, sc_p);

    k_soft<<<NB, 1024, 0, stream>>>(sc_c, sc_p, a_c, a_p);
    k_wsum<<<dim3(NB, 2), 512, 0, stream>>>(drug_h, targ_h, a_c, a_p, (float*)d_out);
}